// Round 2
// baseline (12572.694 us; speedup 1.0000x reference)
//
#include <hip/hip_runtime.h>

#define T_LEN 2050
#define B_SZ 128
#define NCHUNK 33   // ceil(2049/64)
#define HL2PI 0.91893853320467274178f

// ---------- wave-wide helpers (wave = 64 lanes) ----------
__device__ __forceinline__ float waveMax(float v) {
#pragma unroll
    for (int off = 32; off >= 1; off >>= 1)
        v = fmaxf(v, __shfl_xor(v, off, 64));
    return v;
}
__device__ __forceinline__ float waveSum(float v) {
#pragma unroll
    for (int off = 32; off >= 1; off >>= 1)
        v += __shfl_xor(v, off, 64);
    return v;
}
__device__ __forceinline__ void waveArgmax(float& v, int& idx) {
#pragma unroll
    for (int off = 32; off >= 1; off >>= 1) {
        float ov = __shfl_xor(v, off, 64);
        int   oi = __shfl_xor(idx, off, 64);
        if (ov > v || (ov == v && oi < idx)) { v = ov; idx = oi; }
    }
}
// compiler-level memory fence; HW side is covered by same-wave in-order DS ops
__device__ __forceinline__ void cfence() { asm volatile("" ::: "memory"); }

// ======================= emission precompute =======================
// grid: (T*B)/4 blocks x 256 threads; each wave handles one (t,b)
extern "C" __global__ __launch_bounds__(256)
void hmm_emis(const float* __restrict__ x,
              const float* __restrict__ means,
              const float* __restrict__ stds,
              float* __restrict__ lp_out,
              float* __restrict__ m_out)
{
    const int wid = blockIdx.x * 4 + (threadIdx.x >> 6);
    const int j = threadIdx.x & 63;
    const int t = wid >> 7;          // wid = t*128 + b
    const int b = wid & 127;

    const float* xt = x + ((size_t)b * T_LEN + t) * 6;
    float x0 = xt[0], x1 = xt[1], x2 = xt[2], x3 = xt[3];

    float mu0 = means[j * 6 + 0], mu1 = means[j * 6 + 1];
    float mu2 = means[j * 6 + 2], mu3 = means[j * 6 + 3];
    float sg0 = fmaxf(stds[j * 6 + 0], 0.f) + 0.1f;
    float sg1 = fmaxf(stds[j * 6 + 1], 0.f) + 0.1f;
    float sg2 = fmaxf(stds[j * 6 + 2], 0.f) + 0.1f;
    float sg3 = fmaxf(stds[j * 6 + 3], 0.f) + 0.1f;
    float ls0 = logf(sg0), ls1 = logf(sg1), ls2 = logf(sg2), ls3 = logf(sg3);

    // faithful fp32: exact op order of the reference (round-1 proven)
    float z0 = (x0 - mu0) / sg0, z1 = (x1 - mu1) / sg1;
    float z2 = (x2 - mu2) / sg2, z3 = (x3 - mu3) / sg3;
    float e0 = ((-0.5f * z0) * z0 - ls0) - HL2PI;
    float e1 = ((-0.5f * z1) * z1 - ls1) - HL2PI;
    float e2 = ((-0.5f * z2) * z2 - ls2) - HL2PI;
    float e3 = ((-0.5f * z3) * z3 - ls3) - HL2PI;
    float lp = ((e0 + e1) + e2) + e3;

    lp_out[((size_t)t * B_SZ + b) * 64 + j] = lp;
    float mm = waveMax(lp);
    if (j == 0) m_out[(size_t)b * T_LEN + t] = mm;
}

// ======================= main sequential kernel =======================
// blocks 0..127: forward scalers -> out[b]; blocks 128..255: viterbi -> psi,bnd
extern "C" __global__ __launch_bounds__(64, 1)
void hmm_main(const float* __restrict__ x,
              const float* __restrict__ means,
              const float* __restrict__ stds,
              const float* __restrict__ logA_in,
              const float* __restrict__ logpi_in,
              float* __restrict__ out,
              unsigned char* __restrict__ psi,
              unsigned char* __restrict__ bnd,
              const float* __restrict__ lp_pre,
              const float* __restrict__ m_pre,
              int use_pre)
{
    __shared__ float la[64 * 65];
    __shared__ float rowlse[64];
    __shared__ __align__(16) float pbuf[2][64];
    __shared__ unsigned char mt[NCHUNK * 64];

    const int j   = threadIdx.x;
    const int bid = blockIdx.x;
    const bool is_fwd = (bid < B_SZ);
    const int b = is_fwd ? bid : bid - B_SZ;

#pragma unroll
    for (int k = 0; k < 64; ++k)
        la[k * 65 + j] = logA_in[k * 64 + j];
    cfence();

    {   // per-row logsumexp (round-1 exact ops)
        float m = -1e30f;
#pragma unroll
        for (int k = 0; k < 64; ++k) m = fmaxf(m, la[j * 65 + k]);
        float s = 0.f;
#pragma unroll
        for (int k = 0; k < 64; ++k) s += expf(la[j * 65 + k] - m);
        rowlse[j] = m + logf(s);
    }
    cfence();

    float lpi;
    {
        float v = logpi_in[j];
        float m = waveMax(v);
        float s = waveSum(expf(v - m));
        lpi = v - (m + logf(s));
    }

    // emission constants (used only by inline fallback paths)
    float mu0 = means[j * 6 + 0], mu1 = means[j * 6 + 1];
    float mu2 = means[j * 6 + 2], mu3 = means[j * 6 + 3];
    float sg0 = fmaxf(stds[j * 6 + 0], 0.f) + 0.1f;
    float sg1 = fmaxf(stds[j * 6 + 1], 0.f) + 0.1f;
    float sg2 = fmaxf(stds[j * 6 + 2], 0.f) + 0.1f;
    float sg3 = fmaxf(stds[j * 6 + 3], 0.f) + 0.1f;
    float ls0 = logf(sg0), ls1 = logf(sg1), ls2 = logf(sg2), ls3 = logf(sg3);
    const float* xb = x + (size_t)b * T_LEN * 6;

    if (is_fwd) {
        // ============ FORWARD: prob space, deferred rescale ============
        float Ac[64];
#pragma unroll
        for (int i = 0; i < 64; ++i)
            Ac[i] = __expf(la[i * 65 + j] - rowlse[i]);

        float i0 = 1.f / sg0, i1 = 1.f / sg1, i2 = 1.f / sg2, i3 = 1.f / sg3;
        float cst = -(ls0 + ls1 + ls2 + ls3) - 4.f * HL2PI;

        // t = 0
        float lp0;
        if (use_pre) lp0 = lp_pre[(size_t)b * 64 + j];
        else {
            float x0 = xb[0], x1 = xb[1], x2 = xb[2], x3 = xb[3];
            float z0 = (x0 - mu0) * i0, z1 = (x1 - mu1) * i1;
            float z2 = (x2 - mu2) * i2, z3 = (x3 - mu3) * i3;
            lp0 = cst - 0.5f * (z0 * z0 + z1 * z1 + z2 * z2 + z3 * z3);
        }
        float a0 = lp0 + lpi;
        float m0 = waveMax(a0);
        float u = __expf(a0 - m0);
        pbuf[0][j] = u;
        cfence();
        float s = waveSum(u);
        double acc = (double)(m0 + __logf(s));
        float rcp_s = 1.0f / s;

        // prefetch t = 1
        const float* lpp = lp_pre + ((size_t)B_SZ + b) * 64 + j;
        const float* mp  = m_pre + (size_t)b * T_LEN + 1;
        float lp_nx = 0.f, m_nx = 0.f;
        if (use_pre) { lp_nx = *lpp; m_nx = *mp; }

        int cur = 0;
#pragma unroll 1
        for (int t = 1; t < T_LEN; ++t) {
            float lp, mm;
            if (use_pre) {
                lp = lp_nx; mm = m_nx;
                if (t + 1 < T_LEN) { lpp += B_SZ * 64; mp += 1; lp_nx = *lpp; m_nx = *mp; }
            } else {
                const float* xt = xb + t * 6;
                float x0 = xt[0], x1 = xt[1], x2 = xt[2], x3 = xt[3];
                float z0 = (x0 - mu0) * i0, z1 = (x1 - mu1) * i1;
                float z2 = (x2 - mu2) * i2, z3 = (x3 - mu3) * i3;
                lp = cst - 0.5f * (z0 * z0 + z1 * z1 + z2 * z2 + z3 * z3);
                mm = waveMax(lp);
            }
            float e = __expf(lp - mm) * rcp_s;

            const float4* pv = (const float4*)pbuf[cur];
            float q0 = 0.f, q1 = 0.f, q2 = 0.f, q3 = 0.f;
#pragma unroll
            for (int k = 0; k < 16; ++k) {
                float4 pp = pv[k];
                q0 = fmaf(pp.x, Ac[4 * k + 0], q0);
                q1 = fmaf(pp.y, Ac[4 * k + 1], q1);
                q2 = fmaf(pp.z, Ac[4 * k + 2], q2);
                q3 = fmaf(pp.w, Ac[4 * k + 3], q3);
            }
            float q = (q0 + q1) + (q2 + q3);
            float u2 = q * e;
            pbuf[cur ^ 1][j] = u2;
            cfence();
            float s2 = waveSum(u2);
            acc += (double)(mm + __logf(s2));
            rcp_s = 1.0f / s2;
            cur ^= 1;
        }
        if (j == 0) out[b] = (float)acc;
    } else {
        // ============ VITERBI: bit-faithful, barrier-free ============
        float lA[64];
#pragma unroll
        for (int i = 0; i < 64; ++i)
            lA[i] = la[i * 65 + j] - rowlse[i];

        // t = 0
        float lp0;
        if (use_pre) lp0 = lp_pre[(size_t)b * 64 + j];
        else {
            float x0 = xb[0], x1 = xb[1], x2 = xb[2], x3 = xb[3];
            float z0 = (x0 - mu0) / sg0, z1 = (x1 - mu1) / sg1;
            float z2 = (x2 - mu2) / sg2, z3 = (x3 - mu3) / sg3;
            float e0 = ((-0.5f * z0) * z0 - ls0) - HL2PI;
            float e1 = ((-0.5f * z1) * z1 - ls1) - HL2PI;
            float e2 = ((-0.5f * z2) * z2 - ls2) - HL2PI;
            float e3 = ((-0.5f * z3) * z3 - ls3) - HL2PI;
            lp0 = ((e0 + e1) + e2) + e3;
        }
        float dreg = lp0 + lpi;
        pbuf[0][j] = dreg;
        cfence();

        int M = j;
        int cur = 0;
        unsigned char* pp = psi + ((size_t)B_SZ + b) * 64 + j;
        const float* lpp = lp_pre + ((size_t)B_SZ + b) * 64 + j;
        float lp_nx = use_pre ? *lpp : 0.f;

#pragma unroll 1
        for (int t = 1; t < T_LEN; ++t) {
            float lp;
            if (use_pre) {
                lp = lp_nx;
                if (t + 1 < T_LEN) { lpp += B_SZ * 64; lp_nx = *lpp; }
            } else {
                const float* xt = xb + t * 6;
                float x0 = xt[0], x1 = xt[1], x2 = xt[2], x3 = xt[3];
                float z0 = (x0 - mu0) / sg0, z1 = (x1 - mu1) / sg1;
                float z2 = (x2 - mu2) / sg2, z3 = (x3 - mu3) / sg3;
                float e0 = ((-0.5f * z0) * z0 - ls0) - HL2PI;
                float e1 = ((-0.5f * z1) * z1 - ls1) - HL2PI;
                float e2 = ((-0.5f * z2) * z2 - ls2) - HL2PI;
                float e3 = ((-0.5f * z3) * z3 - ls3) - HL2PI;
                lp = ((e0 + e1) + e2) + e3;
            }

            const float4* dv = (const float4*)pbuf[cur];
            float v[64];
#pragma unroll
            for (int k = 0; k < 16; ++k) {
                float4 dd = dv[k];
                v[4 * k + 0] = dd.x + lA[4 * k + 0];
                v[4 * k + 1] = dd.y + lA[4 * k + 1];
                v[4 * k + 2] = dd.z + lA[4 * k + 2];
                v[4 * k + 3] = dd.w + lA[4 * k + 3];
            }
            // tree argmax; pick-right iff strictly greater == numpy first-occurrence
            float av[32]; int ai[32];
#pragma unroll
            for (int k = 0; k < 32; ++k) {
                bool g = v[2 * k + 1] > v[2 * k];
                av[k] = g ? v[2 * k + 1] : v[2 * k];
                ai[k] = g ? 2 * k + 1 : 2 * k;
            }
#pragma unroll
            for (int w = 16; w >= 1; w >>= 1) {
#pragma unroll
                for (int k = 0; k < 32; ++k) {
                    if (k < w) {
                        bool g = av[2 * k + 1] > av[2 * k];
                        av[k] = g ? av[2 * k + 1] : av[2 * k];
                        ai[k] = g ? ai[2 * k + 1] : ai[2 * k];
                    }
                }
            }
            float best = av[0]; int bidx = ai[0];

            dreg = best + lp;
            *pp = (unsigned char)bidx;
            pp += B_SZ * 64;
            M = __shfl(M, bidx, 64);
            pbuf[cur ^ 1][j] = dreg;
            if ((t & 63) == 0 || t == T_LEN - 1) {
                int g = (t == T_LEN - 1) ? (NCHUNK - 1) : (t >> 6) - 1;
                mt[g * 64 + j] = (unsigned char)M;
                M = j;
            }
            cfence();
            cur ^= 1;
        }

        float vv = dreg; int idx = j;
        waveArgmax(vv, idx);
        cfence();
        if (j == 0) {
            int s = idx;
            bnd[b * 34 + 33] = (unsigned char)s;
            for (int g = NCHUNK - 1; g >= 0; --g) {
                s = mt[g * 64 + s];
                bnd[b * 34 + g] = (unsigned char)s;
            }
        }
    }
}

// ======================= parallel backtrack fill =======================
extern "C" __global__ __launch_bounds__(64, 1)
void hmm_fill(const unsigned char* __restrict__ psi,
              const unsigned char* __restrict__ bnd,
              float* __restrict__ out)
{
    const int b = blockIdx.x;
    const int g = threadIdx.x;
    float* oc = out + B_SZ + (size_t)b * T_LEN;
    if (g == NCHUNK) {
        oc[T_LEN - 1] = (float)bnd[b * 34 + 33];
    } else if (g < NCHUNK) {
        const int endt = (g < NCHUNK - 1) ? (g + 1) * 64 : (T_LEN - 1);
        int s = (g < NCHUNK - 1) ? (int)bnd[b * 34 + g + 1] : (int)bnd[b * 34 + 33];
        for (int t = endt; t >= g * 64 + 1; --t) {
            s = psi[((size_t)t * B_SZ + b) * 64 + s];
            oc[t - 1] = (float)s;
        }
    }
}

extern "C" void kernel_launch(void* const* d_in, const int* in_sizes, int n_in,
                              void* d_out, int out_size, void* d_ws, size_t ws_size,
                              hipStream_t stream)
{
    const float* x      = (const float*)d_in[0];
    const float* means  = (const float*)d_in[1];
    const float* stds   = (const float*)d_in[2];
    const float* logA   = (const float*)d_in[3];
    const float* logpi  = (const float*)d_in[4];
    float* out = (float*)d_out;

    size_t psiB  = (size_t)T_LEN * B_SZ * 64;          // 16,793,600
    size_t bndB  = (size_t)B_SZ * 34;                  // 4,352
    size_t offLp = ((psiB + bndB + 255) / 256) * 256;
    size_t lpB   = (size_t)T_LEN * B_SZ * 64 * sizeof(float);  // 67,174,400
    size_t mB    = (size_t)B_SZ * T_LEN * sizeof(float);       // 1,049,600
    size_t need  = offLp + lpB + mB;
    int use_pre  = (ws_size >= need) ? 1 : 0;

    unsigned char* psi = (unsigned char*)d_ws;
    unsigned char* bnd = psi + psiB;
    float* lp_pre = (float*)((char*)d_ws + offLp);
    float* m_pre  = (float*)((char*)d_ws + offLp + lpB);

    if (use_pre) {
        hipLaunchKernelGGL(hmm_emis, dim3((T_LEN * B_SZ) / 4), dim3(256), 0, stream,
                           x, means, stds, lp_pre, m_pre);
    }
    hipLaunchKernelGGL(hmm_main, dim3(2 * B_SZ), dim3(64), 0, stream,
                       x, means, stds, logA, logpi, out, psi, bnd,
                       lp_pre, m_pre, use_pre);
    hipLaunchKernelGGL(hmm_fill, dim3(B_SZ), dim3(64), 0, stream, psi, bnd, out);
}

// Round 3
// 12403.305 us; speedup vs baseline: 1.0137x; 1.0137x over previous
//
#include <hip/hip_runtime.h>

#define T_LEN 2050
#define B_SZ 128
#define NCHUNK 33           // ceil(2049/64) backtrack chunks
#define NGRP 513            // ceil(2049/4) packed-psi groups
#define HL2PI 0.91893853320467274178f

// ---------- wave-wide helpers (wave = 64 lanes) ----------
__device__ __forceinline__ float waveMax(float v) {
#pragma unroll
    for (int off = 32; off >= 1; off >>= 1)
        v = fmaxf(v, __shfl_xor(v, off, 64));
    return v;
}
__device__ __forceinline__ float waveSum(float v) {
#pragma unroll
    for (int off = 32; off >= 1; off >>= 1)
        v += __shfl_xor(v, off, 64);
    return v;
}
__device__ __forceinline__ void waveArgmax(float& v, int& idx) {
#pragma unroll
    for (int off = 32; off >= 1; off >>= 1) {
        float ov = __shfl_xor(v, off, 64);
        int   oi = __shfl_xor(idx, off, 64);
        if (ov > v || (ov == v && oi < idx)) { v = ov; idx = oi; }
    }
}
// compiler-level memory fence; HW ordering is same-wave in-order DS ops
__device__ __forceinline__ void cfence() { asm volatile("" ::: "memory"); }

// blocks 0..127: forward scalers -> out[b]
// blocks 128..255: viterbi -> psi (packed), bnd
extern "C" __global__ __launch_bounds__(64, 1)
void hmm_main(const float* __restrict__ x,
              const float* __restrict__ means,
              const float* __restrict__ stds,
              const float* __restrict__ logA_in,
              const float* __restrict__ logpi_in,
              float* __restrict__ out,
              unsigned int* __restrict__ psi,      // [NGRP][B][64] dwords, byte k = step 4g+1+k
              unsigned char* __restrict__ bnd)
{
    __shared__ float la[64 * 65];
    __shared__ float rowlse[64];
    __shared__ __align__(16) float pbuf[2][64];
    __shared__ unsigned char mt[NCHUNK * 64];

    const int j   = threadIdx.x;
    const int bid = blockIdx.x;
    const bool is_fwd = (bid < B_SZ);
    const int b = is_fwd ? bid : bid - B_SZ;

#pragma unroll
    for (int k = 0; k < 64; ++k)
        la[k * 65 + j] = logA_in[k * 64 + j];
    cfence();

    {   // per-row logsumexp of log_A (exact op order, round-1 proven)
        float m = -1e30f;
#pragma unroll
        for (int k = 0; k < 64; ++k) m = fmaxf(m, la[j * 65 + k]);
        float s = 0.f;
#pragma unroll
        for (int k = 0; k < 64; ++k) s += expf(la[j * 65 + k] - m);
        rowlse[j] = m + logf(s);
    }
    cfence();

    float lpi;
    {
        float v = logpi_in[j];
        float m = waveMax(v);
        float s = waveSum(expf(v - m));
        lpi = v - (m + logf(s));
    }

    // emission constants for state j (dims 0..3)
    float mu0 = means[j * 6 + 0], mu1 = means[j * 6 + 1];
    float mu2 = means[j * 6 + 2], mu3 = means[j * 6 + 3];
    float sg0 = fmaxf(stds[j * 6 + 0], 0.f) + 0.1f;
    float sg1 = fmaxf(stds[j * 6 + 1], 0.f) + 0.1f;
    float sg2 = fmaxf(stds[j * 6 + 2], 0.f) + 0.1f;
    float sg3 = fmaxf(stds[j * 6 + 3], 0.f) + 0.1f;
    float ls0 = logf(sg0), ls1 = logf(sg1), ls2 = logf(sg2), ls3 = logf(sg3);
    const float* xb = x + (size_t)b * T_LEN * 6;   // x addresses are wave-uniform -> scalar loads

    if (is_fwd) {
        // ============ FORWARD: prob space, deferred rescale ============
        float Ac[64];
#pragma unroll
        for (int i = 0; i < 64; ++i)
            Ac[i] = __expf(la[i * 65 + j] - rowlse[i]);

        float i0 = 1.f / sg0, i1 = 1.f / sg1, i2 = 1.f / sg2, i3 = 1.f / sg3;
        float cst = -(ls0 + ls1 + ls2 + ls3) - 4.f * HL2PI;

        // t = 0
        float x0 = xb[0], x1 = xb[1], x2 = xb[2], x3 = xb[3];
        float z0 = (x0 - mu0) * i0, z1 = (x1 - mu1) * i1;
        float z2 = (x2 - mu2) * i2, z3 = (x3 - mu3) * i3;
        float lp0 = cst - 0.5f * (z0 * z0 + z1 * z1 + z2 * z2 + z3 * z3);
        float a0 = lp0 + lpi;
        float m0 = waveMax(a0);
        float u = __expf(a0 - m0);
        pbuf[0][j] = u;
        cfence();
        float s = waveSum(u);
        double acc = (double)(m0 + __logf(s));
        float rcp_s = 1.0f / s;

        int cur = 0;
#pragma unroll 4
        for (int t = 1; t < T_LEN; ++t) {
            const float* xt = xb + t * 6;
            float y0 = xt[0], y1 = xt[1], y2 = xt[2], y3 = xt[3];
            float w0 = (y0 - mu0) * i0, w1 = (y1 - mu1) * i1;
            float w2 = (y2 - mu2) * i2, w3 = (y3 - mu3) * i3;
            float lp = cst - 0.5f * (w0 * w0 + w1 * w1 + w2 * w2 + w3 * w3);
            float mm = waveMax(lp);
            float e = __expf(lp - mm) * rcp_s;

            const float4* pv = (const float4*)pbuf[cur];
            float q0 = 0.f, q1 = 0.f, q2 = 0.f, q3 = 0.f;
#pragma unroll
            for (int k = 0; k < 16; ++k) {
                float4 pp = pv[k];
                q0 = fmaf(pp.x, Ac[4 * k + 0], q0);
                q1 = fmaf(pp.y, Ac[4 * k + 1], q1);
                q2 = fmaf(pp.z, Ac[4 * k + 2], q2);
                q3 = fmaf(pp.w, Ac[4 * k + 3], q3);
            }
            float q = (q0 + q1) + (q2 + q3);
            float u2 = q * e;
            pbuf[cur ^ 1][j] = u2;
            cfence();
            float s2 = waveSum(u2);
            acc += (double)(mm + __logf(s2));
            rcp_s = 1.0f / s2;
            cur ^= 1;
        }
        if (j == 0) out[b] = (float)acc;
    } else {
        // ============ VITERBI: bit-faithful, barrier-free, packed psi ============
        float lA[64];
#pragma unroll
        for (int i = 0; i < 64; ++i)
            lA[i] = la[i * 65 + j] - rowlse[i];

        // t = 0 (exact reference op order)
        float x0 = xb[0], x1 = xb[1], x2 = xb[2], x3 = xb[3];
        float z0 = (x0 - mu0) / sg0, z1 = (x1 - mu1) / sg1;
        float z2 = (x2 - mu2) / sg2, z3 = (x3 - mu3) / sg3;
        float e0 = ((-0.5f * z0) * z0 - ls0) - HL2PI;
        float e1 = ((-0.5f * z1) * z1 - ls1) - HL2PI;
        float e2 = ((-0.5f * z2) * z2 - ls2) - HL2PI;
        float e3 = ((-0.5f * z3) * z3 - ls3) - HL2PI;
        float dreg = (((e0 + e1) + e2) + e3) + lpi;
        pbuf[0][j] = dreg;
        cfence();

        int M = j;
        int cur = 0;
        unsigned int pk = 0;
#pragma unroll 4
        for (int t = 1; t < T_LEN; ++t) {
            const float* xt = xb + t * 6;
            float y0 = xt[0], y1 = xt[1], y2 = xt[2], y3 = xt[3];
            float w0 = (y0 - mu0) / sg0, w1 = (y1 - mu1) / sg1;
            float w2 = (y2 - mu2) / sg2, w3 = (y3 - mu3) / sg3;
            float f0 = ((-0.5f * w0) * w0 - ls0) - HL2PI;
            float f1 = ((-0.5f * w1) * w1 - ls1) - HL2PI;
            float f2 = ((-0.5f * w2) * w2 - ls2) - HL2PI;
            float f3 = ((-0.5f * w3) * w3 - ls3) - HL2PI;
            float lp = ((f0 + f1) + f2) + f3;

            const float4* dv = (const float4*)pbuf[cur];
            float v[64];
#pragma unroll
            for (int k = 0; k < 16; ++k) {
                float4 dd = dv[k];
                v[4 * k + 0] = dd.x + lA[4 * k + 0];
                v[4 * k + 1] = dd.y + lA[4 * k + 1];
                v[4 * k + 2] = dd.z + lA[4 * k + 2];
                v[4 * k + 3] = dd.w + lA[4 * k + 3];
            }
            // tree argmax; pick-right iff strictly greater == numpy first-occurrence
            float av[32]; int ai[32];
#pragma unroll
            for (int k = 0; k < 32; ++k) {
                bool g = v[2 * k + 1] > v[2 * k];
                av[k] = g ? v[2 * k + 1] : v[2 * k];
                ai[k] = g ? 2 * k + 1 : 2 * k;
            }
#pragma unroll
            for (int w = 16; w >= 1; w >>= 1) {
#pragma unroll
                for (int k = 0; k < 32; ++k) {
                    if (k < w) {
                        bool g = av[2 * k + 1] > av[2 * k];
                        av[k] = g ? av[2 * k + 1] : av[2 * k];
                        ai[k] = g ? ai[2 * k + 1] : ai[2 * k];
                    }
                }
            }
            float best = av[0]; int bidx = ai[0];

            dreg = best + lp;
            int slot = (t - 1) & 3;
            pk |= (unsigned int)bidx << (slot * 8);
            if (slot == 3 || t == T_LEN - 1) {
                psi[((size_t)((t - 1) >> 2) * B_SZ + b) * 64 + j] = pk;
                pk = 0;
            }
            M = __shfl(M, bidx, 64);
            pbuf[cur ^ 1][j] = dreg;
            if ((t & 63) == 0 || t == T_LEN - 1) {
                int g = (t == T_LEN - 1) ? (NCHUNK - 1) : (t >> 6) - 1;
                mt[g * 64 + j] = (unsigned char)M;
                M = j;
            }
            cfence();
            cur ^= 1;
        }

        float vv = dreg; int idx = j;
        waveArgmax(vv, idx);
        cfence();
        if (j == 0) {
            int s2 = idx;
            bnd[b * 34 + 33] = (unsigned char)s2;
            for (int g = NCHUNK - 1; g >= 0; --g) {
                s2 = mt[g * 64 + s2];
                bnd[b * 34 + g] = (unsigned char)s2;
            }
        }
    }
}

// ======================= parallel backtrack fill =======================
// block = batch b, lane = chunk g. psi byte for (t, state s):
// dword (( (t-1)>>2 )*B + b)*64 + s, byte lane (t-1)&3.
extern "C" __global__ __launch_bounds__(64, 1)
void hmm_fill(const unsigned int* __restrict__ psi,
              const unsigned char* __restrict__ bnd,
              float* __restrict__ out)
{
    const unsigned char* pb = (const unsigned char*)psi;
    const int b = blockIdx.x;
    const int g = threadIdx.x;
    float* oc = out + B_SZ + (size_t)b * T_LEN;
    if (g == NCHUNK) {
        oc[T_LEN - 1] = (float)bnd[b * 34 + 33];
    } else if (g < NCHUNK) {
        const int endt = (g < NCHUNK - 1) ? (g + 1) * 64 : (T_LEN - 1);
        int s = (g < NCHUNK - 1) ? (int)bnd[b * 34 + g + 1] : (int)bnd[b * 34 + 33];
        for (int t = endt; t >= g * 64 + 1; --t) {
            s = pb[((size_t)((t - 1) >> 2) * B_SZ + b) * 256 + s * 4 + ((t - 1) & 3)];
            oc[t - 1] = (float)s;
        }
    }
}

extern "C" void kernel_launch(void* const* d_in, const int* in_sizes, int n_in,
                              void* d_out, int out_size, void* d_ws, size_t ws_size,
                              hipStream_t stream)
{
    const float* x      = (const float*)d_in[0];
    const float* means  = (const float*)d_in[1];
    const float* stds   = (const float*)d_in[2];
    const float* logA   = (const float*)d_in[3];
    const float* logpi  = (const float*)d_in[4];
    float* out = (float*)d_out;

    size_t psiB = (size_t)NGRP * B_SZ * 64 * 4;   // 16,809,984 B
    unsigned int*  psi = (unsigned int*)d_ws;
    unsigned char* bnd = (unsigned char*)d_ws + psiB;

    hipLaunchKernelGGL(hmm_main, dim3(2 * B_SZ), dim3(64), 0, stream,
                       x, means, stds, logA, logpi, out, psi, bnd);
    hipLaunchKernelGGL(hmm_fill, dim3(B_SZ), dim3(64), 0, stream, psi, bnd, out);
}

// Round 4
// 1984.386 us; speedup vs baseline: 6.3358x; 6.2504x over previous
//
#include <hip/hip_runtime.h>

#define T_LEN 2050
#define B_SZ 128
#define C_SZ 64
#define NCHUNK 33   // ceil(2049/64): chunks of psi steps t=1..2049

// ---------- wave-wide helpers (wave = 64 lanes) ----------
__device__ __forceinline__ float waveMax(float v) {
#pragma unroll
    for (int off = 32; off >= 1; off >>= 1)
        v = fmaxf(v, __shfl_xor(v, off, 64));
    return v;
}
__device__ __forceinline__ float waveSum(float v) {
#pragma unroll
    for (int off = 32; off >= 1; off >>= 1)
        v += __shfl_xor(v, off, 64);
    return v;
}
// argmax with first-occurrence (lowest index) tie-break, all lanes get result
__device__ __forceinline__ void waveArgmax(float& v, int& idx) {
#pragma unroll
    for (int off = 32; off >= 1; off >>= 1) {
        float ov = __shfl_xor(v, off, 64);
        int   oi = __shfl_xor(idx, off, 64);
        if (ov > v || (ov == v && oi < idx)) { v = ov; idx = oi; }
    }
}
// compile-time ordering only; HW side: single-wave blocks + in-order DS pipe
// (bit-exactness of this handoff proven in rounds 2/3, absmax 0.0)
__device__ __forceinline__ void cfence() { asm volatile("" ::: "memory"); }

// blocks 0..127: forward scalers for b = blockIdx.x      -> out[b]
// blocks 128..255: viterbi fwd for b = blockIdx.x - 128  -> psi, bnd
extern "C" __global__ __launch_bounds__(64, 1)
void hmm_main(const float* __restrict__ x,
              const float* __restrict__ means,
              const float* __restrict__ stds,
              const float* __restrict__ logA_in,
              const float* __restrict__ logpi_in,
              float* __restrict__ out,
              unsigned char* __restrict__ psi,
              unsigned char* __restrict__ bnd)
{
    __shared__ float la[64 * 65];        // padded log_A staging
    __shared__ float rowlse[64];
    __shared__ __align__(16) float pbuf[2][64];   // p (fwd) or delta (viterbi), double buffered
    __shared__ unsigned char mt[NCHUNK * 64];     // composed backpointer tables

    const int j   = threadIdx.x;          // state index
    const int bid = blockIdx.x;
    const bool is_fwd = (bid < B_SZ);
    const int b = is_fwd ? bid : bid - B_SZ;

    // ---- stage log_A into LDS (padded stride 65), coalesced ----
#pragma unroll
    for (int k = 0; k < 64; ++k)
        la[k * 65 + j] = logA_in[k * 64 + j];
    cfence();

    // ---- per-row logsumexp: lane j handles row j (conflict-free: stride 65) ----
    {
        float m = -1e30f;
#pragma unroll
        for (int k = 0; k < 64; ++k) m = fmaxf(m, la[j * 65 + k]);
        float s = 0.f;
#pragma unroll
        for (int k = 0; k < 64; ++k) s += expf(la[j * 65 + k] - m);
        rowlse[j] = m + logf(s);
    }
    cfence();

    // ---- log_softmax(log_pi) ----
    float lpi;
    {
        float v = logpi_in[j];
        float m = waveMax(v);
        float s = waveSum(expf(v - m));
        lpi = v - (m + logf(s));
    }

    // ---- emission constants for state j (only dims 0..3 used) ----
    const float HL2PI = 0.91893853320467274178f;   // 0.5*log(2*pi)
    float mu0 = means[j * 6 + 0], mu1 = means[j * 6 + 1];
    float mu2 = means[j * 6 + 2], mu3 = means[j * 6 + 3];
    float sg0 = fmaxf(stds[j * 6 + 0], 0.f) + 0.1f;
    float sg1 = fmaxf(stds[j * 6 + 1], 0.f) + 0.1f;
    float sg2 = fmaxf(stds[j * 6 + 2], 0.f) + 0.1f;
    float sg3 = fmaxf(stds[j * 6 + 3], 0.f) + 0.1f;
    float ls0 = logf(sg0), ls1 = logf(sg1), ls2 = logf(sg2), ls3 = logf(sg3);

    const float* xb = x + (size_t)b * T_LEN * 6;

    if (is_fwd) {
        // =================== FORWARD (prob space) ===================
        float Acol[64];   // column j of A = softmax(log_A, rows)
#pragma unroll
        for (int i = 0; i < 64; ++i)
            Acol[i] = __expf(la[i * 65 + j] - rowlse[i]);

        float i0 = 1.f / sg0, i1 = 1.f / sg1, i2 = 1.f / sg2, i3 = 1.f / sg3;
        float cst = -(ls0 + ls1 + ls2 + ls3) - 4.f * HL2PI;

        double acc;
        int cur = 0;
        {   // t = 0
            float x0 = xb[0], x1 = xb[1], x2 = xb[2], x3 = xb[3];
            float z0 = (x0 - mu0) * i0, z1 = (x1 - mu1) * i1;
            float z2 = (x2 - mu2) * i2, z3 = (x3 - mu3) * i3;
            float lp = cst - 0.5f * (z0 * z0 + z1 * z1 + z2 * z2 + z3 * z3);
            float a = lp + lpi;
            float m = waveMax(a);
            float e = __expf(a - m);
            float s = waveSum(e);
            float st = m + __logf(s);
            acc = (double)st;
            pbuf[0][j] = e * (1.f / s);
        }
        cfence();

        for (int t = 1; t < T_LEN; ++t) {
            const float* xt = xb + t * 6;
            float x0 = xt[0], x1 = xt[1], x2 = xt[2], x3 = xt[3];
            float z0 = (x0 - mu0) * i0, z1 = (x1 - mu1) * i1;
            float z2 = (x2 - mu2) * i2, z3 = (x3 - mu3) * i3;
            float lp = cst - 0.5f * (z0 * z0 + z1 * z1 + z2 * z2 + z3 * z3);

            const float4* pv = (const float4*)pbuf[cur];
            float q0 = 0.f, q1 = 0.f, q2 = 0.f, q3 = 0.f;
#pragma unroll
            for (int k = 0; k < 16; ++k) {
                float4 pp = pv[k];
                q0 = fmaf(pp.x, Acol[4 * k + 0], q0);
                q1 = fmaf(pp.y, Acol[4 * k + 1], q1);
                q2 = fmaf(pp.z, Acol[4 * k + 2], q2);
                q3 = fmaf(pp.w, Acol[4 * k + 3], q3);
            }
            float q = (q0 + q1) + (q2 + q3);
            float a = lp + __logf(q);
            float m = waveMax(a);
            float e = __expf(a - m);
            float s = waveSum(e);
            float st = m + __logf(s);
            acc += (double)st;
            pbuf[cur ^ 1][j] = e * (1.f / s);
            cfence();
            cur ^= 1;
        }
        if (j == 0) out[b] = (float)acc;
    } else {
        // =================== VITERBI (log space, faithful fp32) ===================
        float lAcol[64];   // column j of log_softmax(log_A)
#pragma unroll
        for (int i = 0; i < 64; ++i)
            lAcol[i] = la[i * 65 + j] - rowlse[i];

        int M = j;          // composed backpointer within current chunk
        float dreg;
        int cur = 0;
        {   // t = 0
            float x0 = xb[0], x1 = xb[1], x2 = xb[2], x3 = xb[3];
            float z0 = (x0 - mu0) / sg0, z1 = (x1 - mu1) / sg1;
            float z2 = (x2 - mu2) / sg2, z3 = (x3 - mu3) / sg3;
            float e0 = ((-0.5f * z0) * z0 - ls0) - HL2PI;
            float e1 = ((-0.5f * z1) * z1 - ls1) - HL2PI;
            float e2 = ((-0.5f * z2) * z2 - ls2) - HL2PI;
            float e3 = ((-0.5f * z3) * z3 - ls3) - HL2PI;
            float lp = ((e0 + e1) + e2) + e3;
            dreg = lp + lpi;
            pbuf[0][j] = dreg;
        }
        cfence();

        for (int t = 1; t < T_LEN; ++t) {
            const float* xt = xb + t * 6;
            float x0 = xt[0], x1 = xt[1], x2 = xt[2], x3 = xt[3];
            float z0 = (x0 - mu0) / sg0, z1 = (x1 - mu1) / sg1;
            float z2 = (x2 - mu2) / sg2, z3 = (x3 - mu3) / sg3;
            float e0 = ((-0.5f * z0) * z0 - ls0) - HL2PI;
            float e1 = ((-0.5f * z1) * z1 - ls1) - HL2PI;
            float e2 = ((-0.5f * z2) * z2 - ls2) - HL2PI;
            float e3 = ((-0.5f * z3) * z3 - ls3) - HL2PI;
            float lp = ((e0 + e1) + e2) + e3;

            const float4* dv = (const float4*)pbuf[cur];
            float bv0 = -3.4e38f, bv1 = -3.4e38f, bv2 = -3.4e38f, bv3 = -3.4e38f;
            int bi0 = 0, bi1 = 1, bi2 = 2, bi3 = 3;
#pragma unroll
            for (int k = 0; k < 16; ++k) {
                float4 dd = dv[k];
                float v0 = dd.x + lAcol[4 * k + 0];
                float v1 = dd.y + lAcol[4 * k + 1];
                float v2 = dd.z + lAcol[4 * k + 2];
                float v3 = dd.w + lAcol[4 * k + 3];
                if (v0 > bv0) { bv0 = v0; bi0 = 4 * k + 0; }
                if (v1 > bv1) { bv1 = v1; bi1 = 4 * k + 1; }
                if (v2 > bv2) { bv2 = v2; bi2 = 4 * k + 2; }
                if (v3 > bv3) { bv3 = v3; bi3 = 4 * k + 3; }
            }
            // merge trackers; exact ties -> smallest i (np.argmax semantics)
            float best = bv0; int bidx = bi0;
            if (bv1 > best || (bv1 == best && bi1 < bidx)) { best = bv1; bidx = bi1; }
            if (bv2 > best || (bv2 == best && bi2 < bidx)) { best = bv2; bidx = bi2; }
            if (bv3 > best || (bv3 == best && bi3 < bidx)) { best = bv3; bidx = bi3; }

            dreg = best + lp;
            psi[((size_t)t * B_SZ + b) * 64 + j] = (unsigned char)bidx;
            M = __shfl(M, bidx, 64);           // compose backpointers
            pbuf[cur ^ 1][j] = dreg;
            if ((t & 63) == 0 || t == T_LEN - 1) {
                int g = (t == T_LEN - 1) ? (NCHUNK - 1) : (t >> 6) - 1;
                mt[g * 64 + j] = (unsigned char)M;
                M = j;
            }
            cfence();
            cur ^= 1;
        }

        // c_last = argmax_j d_last (first occurrence on tie)
        float v = dreg; int idx = j;
        waveArgmax(v, idx);
        cfence();
        if (j == 0) {
            int s = idx;
            bnd[b * 34 + 33] = (unsigned char)s;       // state at t = 2049
            for (int g = NCHUNK - 1; g >= 0; --g) {    // boundary walk via LDS tables
                s = mt[g * 64 + s];
                bnd[b * 34 + g] = (unsigned char)s;    // state at t = 64*g
            }
        }
    }
}

// Parallel within-chunk backtrack fill: block = batch b, lane = chunk g
extern "C" __global__ __launch_bounds__(64, 1)
void hmm_fill(const unsigned char* __restrict__ psi,
              const unsigned char* __restrict__ bnd,
              float* __restrict__ out)
{
    const int b = blockIdx.x;
    const int g = threadIdx.x;
    float* oc = out + B_SZ + (size_t)b * T_LEN;
    if (g == NCHUNK) {
        oc[T_LEN - 1] = (float)bnd[b * 34 + 33];
    } else if (g < NCHUNK) {
        const int endt = (g < NCHUNK - 1) ? (g + 1) * 64 : (T_LEN - 1);
        int s = (g < NCHUNK - 1) ? (int)bnd[b * 34 + g + 1] : (int)bnd[b * 34 + 33];
        for (int t = endt; t >= g * 64 + 1; --t) {
            s = psi[((size_t)t * B_SZ + b) * 64 + s];
            oc[t - 1] = (float)s;
        }
    }
}

extern "C" void kernel_launch(void* const* d_in, const int* in_sizes, int n_in,
                              void* d_out, int out_size, void* d_ws, size_t ws_size,
                              hipStream_t stream)
{
    const float* x      = (const float*)d_in[0];
    const float* means  = (const float*)d_in[1];
    const float* stds   = (const float*)d_in[2];
    const float* logA   = (const float*)d_in[3];
    const float* logpi  = (const float*)d_in[4];
    float* out = (float*)d_out;

    unsigned char* psi = (unsigned char*)d_ws;                       // [2050][128][64] bytes (t=0 unused)
    unsigned char* bnd = psi + (size_t)T_LEN * B_SZ * 64;            // [128][34] bytes

    hipLaunchKernelGGL(hmm_main, dim3(2 * B_SZ), dim3(64), 0, stream,
                       x, means, stds, logA, logpi, out, psi, bnd);
    hipLaunchKernelGGL(hmm_fill, dim3(B_SZ), dim3(64), 0, stream, psi, bnd, out);
}

// Round 5
// 1723.955 us; speedup vs baseline: 7.2929x; 1.1511x over previous
//
#include <hip/hip_runtime.h>

#define T_LEN 2050
#define B_SZ 128
#define NCHUNK 33               // chunks of steps t=1..2049 (32 full + 1 single)
#define HL2PI 0.91893853320467274178f

// ---------- wave-wide helpers (wave = 64 lanes) ----------
__device__ __forceinline__ float waveMax(float v) {
#pragma unroll
    for (int off = 32; off >= 1; off >>= 1)
        v = fmaxf(v, __shfl_xor(v, off, 64));
    return v;
}
__device__ __forceinline__ float waveSum(float v) {
#pragma unroll
    for (int off = 32; off >= 1; off >>= 1)
        v += __shfl_xor(v, off, 64);
    return v;
}
__device__ __forceinline__ void waveArgmax(float& v, int& idx) {
#pragma unroll
    for (int off = 32; off >= 1; off >>= 1) {
        float ov = __shfl_xor(v, off, 64);
        int   oi = __shfl_xor(idx, off, 64);
        if (ov > v || (ov == v && oi < idx)) { v = ov; idx = oi; }
    }
}
__device__ __forceinline__ void cfence() { asm volatile("" ::: "memory"); }

// DPP full-wave reductions (gfx9 row_shr + row_bcast), result broadcast via readlane 63.
// Sum: bound_ctrl=1 -> invalid lanes contribute 0.  Max: old=v -> invalid lanes keep v.
__device__ __forceinline__ float dppSumAll(float v) {
#define SSTEP(ctrl) { int t_ = __builtin_amdgcn_update_dpp(0, __float_as_int(v), ctrl, 0xf, 0xf, true); \
                      v = v + __int_as_float(t_); }
    SSTEP(0x111) SSTEP(0x112) SSTEP(0x114) SSTEP(0x118) SSTEP(0x142) SSTEP(0x143)
#undef SSTEP
    return __int_as_float(__builtin_amdgcn_readlane(__float_as_int(v), 63));
}
__device__ __forceinline__ float dppMaxAll(float v) {
#define MSTEP(ctrl) { int t_ = __builtin_amdgcn_update_dpp(__float_as_int(v), __float_as_int(v), ctrl, 0xf, 0xf, false); \
                      v = fmaxf(v, __int_as_float(t_)); }
    MSTEP(0x111) MSTEP(0x112) MSTEP(0x114) MSTEP(0x118) MSTEP(0x142) MSTEP(0x143)
#undef MSTEP
    return __int_as_float(__builtin_amdgcn_readlane(__float_as_int(v), 63));
}

// ===== prep: log_softmax(log_A) -> lAg[j*64+i] (column-major), log_softmax(log_pi) =====
extern "C" __global__ __launch_bounds__(64, 1)
void hmm_prep(const float* __restrict__ logA_in,
              const float* __restrict__ logpi_in,
              float* __restrict__ lAg,
              float* __restrict__ lpig)
{
    __shared__ float la[64 * 65];
    __shared__ float rowlse[64];
    const int j = threadIdx.x;
#pragma unroll
    for (int k = 0; k < 64; ++k)
        la[k * 65 + j] = logA_in[k * 64 + j];
    cfence();
    {   // exact op order (round-1/4 proven)
        float m = -1e30f;
#pragma unroll
        for (int k = 0; k < 64; ++k) m = fmaxf(m, la[j * 65 + k]);
        float s = 0.f;
#pragma unroll
        for (int k = 0; k < 64; ++k) s += expf(la[j * 65 + k] - m);
        rowlse[j] = m + logf(s);
    }
    cfence();
    {
        float v = logpi_in[j];
        float m = waveMax(v);
        float s = waveSum(expf(v - m));
        lpig[j] = v - (m + logf(s));
    }
    float4* o = (float4*)lAg;
#pragma unroll
    for (int k = 0; k < 16; ++k) {
        float4 v;
        v.x = la[(4 * k + 0) * 65 + j] - rowlse[4 * k + 0];
        v.y = la[(4 * k + 1) * 65 + j] - rowlse[4 * k + 1];
        v.z = la[(4 * k + 2) * 65 + j] - rowlse[4 * k + 2];
        v.w = la[(4 * k + 3) * 65 + j] - rowlse[4 * k + 3];
        o[j * 16 + k] = v;
    }
}

// ===== main sequential kernel: blocks 0..127 forward -> out[b]; 128..255 viterbi -> dstore, c_last =====
extern "C" __global__ __launch_bounds__(64, 1)
void hmm_main(const float* __restrict__ x,
              const float* __restrict__ means,
              const float* __restrict__ stds,
              const float* __restrict__ lAg,
              const float* __restrict__ lpig,
              float* __restrict__ out,
              float* __restrict__ dstore,
              int* __restrict__ c_last)
{
    __shared__ __align__(16) float xs[12304];     // x[b] raw: [t*6+d], 49.2 KB
    __shared__ __align__(16) float pbuf[2][64];

    const int j   = threadIdx.x;
    const int bid = blockIdx.x;
    const bool is_fwd = (bid < B_SZ);
    const int b = is_fwd ? bid : bid - B_SZ;

    // stage x (coalesced float4)
    {
        const float4* xg4 = (const float4*)(x + (size_t)b * T_LEN * 6);
        float4* xs4 = (float4*)xs;
        for (int i = j; i < 3075; i += 64) xs4[i] = xg4[i];
    }
    float lpi = lpig[j];

    // emission constants
    float mu0 = means[j * 6 + 0], mu1 = means[j * 6 + 1];
    float mu2 = means[j * 6 + 2], mu3 = means[j * 6 + 3];
    float sg0 = fmaxf(stds[j * 6 + 0], 0.f) + 0.1f;
    float sg1 = fmaxf(stds[j * 6 + 1], 0.f) + 0.1f;
    float sg2 = fmaxf(stds[j * 6 + 2], 0.f) + 0.1f;
    float sg3 = fmaxf(stds[j * 6 + 3], 0.f) + 0.1f;
    float ls0 = logf(sg0), ls1 = logf(sg1), ls2 = logf(sg2), ls3 = logf(sg3);
    cfence();   // xs staged (same-wave in-order DS)

    if (is_fwd) {
        // ---------- FORWARD: prob space, deferred rescale (round-2 proven math), DPP reductions ----------
        float Ac[64];
        {
            const float4* g = (const float4*)lAg;
#pragma unroll
            for (int k = 0; k < 16; ++k) {
                float4 v = g[j * 16 + k];
                Ac[4 * k + 0] = __expf(v.x);
                Ac[4 * k + 1] = __expf(v.y);
                Ac[4 * k + 2] = __expf(v.z);
                Ac[4 * k + 3] = __expf(v.w);
            }
        }
        float i0 = 1.f / sg0, i1 = 1.f / sg1, i2 = 1.f / sg2, i3 = 1.f / sg3;
        float cst = -(ls0 + ls1 + ls2 + ls3) - 4.f * HL2PI;

        // t = 0
        float z0 = (xs[0] - mu0) * i0, z1 = (xs[1] - mu1) * i1;
        float z2 = (xs[2] - mu2) * i2, z3 = (xs[3] - mu3) * i3;
        float lp0 = cst - 0.5f * (z0 * z0 + z1 * z1 + z2 * z2 + z3 * z3);
        float a0 = lp0 + lpi;
        float m0a = dppMaxAll(a0);
        float u = __expf(a0 - m0a);
        pbuf[0][j] = u;
        cfence();
        float s = dppSumAll(u);
        double acc = (double)(m0a + __logf(s));
        float rcp_s = 1.0f / s;

        // pipeline: emission for t=1
        float lpc, mmc;
        {
            int t6 = 6;
            float w0 = (xs[t6] - mu0) * i0, w1 = (xs[t6 + 1] - mu1) * i1;
            float w2 = (xs[t6 + 2] - mu2) * i2, w3 = (xs[t6 + 3] - mu3) * i3;
            lpc = cst - 0.5f * (w0 * w0 + w1 * w1 + w2 * w2 + w3 * w3);
            mmc = dppMaxAll(lpc);
        }

        int cur = 0;
#pragma unroll 1
        for (int t = 1; t < T_LEN; ++t) {
            // compute next step's emission early (overlaps with recurrence)
            float lpn = 0.f, mmn = 0.f;
            if (t + 1 < T_LEN) {
                int t6 = (t + 1) * 6;
                float w0 = (xs[t6] - mu0) * i0, w1 = (xs[t6 + 1] - mu1) * i1;
                float w2 = (xs[t6 + 2] - mu2) * i2, w3 = (xs[t6 + 3] - mu3) * i3;
                lpn = cst - 0.5f * (w0 * w0 + w1 * w1 + w2 * w2 + w3 * w3);
                mmn = dppMaxAll(lpn);
            }
            float e = __expf(lpc - mmc) * rcp_s;

            const float4* pv = (const float4*)pbuf[cur];
            float q0 = 0.f, q1 = 0.f, q2 = 0.f, q3 = 0.f;
#pragma unroll
            for (int k = 0; k < 16; ++k) {
                float4 pp = pv[k];
                q0 = fmaf(pp.x, Ac[4 * k + 0], q0);
                q1 = fmaf(pp.y, Ac[4 * k + 1], q1);
                q2 = fmaf(pp.z, Ac[4 * k + 2], q2);
                q3 = fmaf(pp.w, Ac[4 * k + 3], q3);
            }
            float q = (q0 + q1) + (q2 + q3);
            float u2 = q * e;
            pbuf[cur ^ 1][j] = u2;
            cfence();
            float s2 = dppSumAll(u2);
            acc += (double)(mmc + __logf(s2));
            rcp_s = 1.0f / s2;
            cur ^= 1; lpc = lpn; mmc = mmn;
        }
        if (j == 0) out[b] = (float)acc;
    } else {
        // ---------- VITERBI: values-only recurrence (bit-exact), d streamed to global ----------
        float lA[64];
        {
            const float4* g = (const float4*)lAg;
#pragma unroll
            for (int k = 0; k < 16; ++k) {
                float4 v = g[j * 16 + k];
                lA[4 * k + 0] = v.x; lA[4 * k + 1] = v.y;
                lA[4 * k + 2] = v.z; lA[4 * k + 3] = v.w;
            }
        }
        // t = 0 (exact reference op order)
        float z0 = (xs[0] - mu0) / sg0, z1 = (xs[1] - mu1) / sg1;
        float z2 = (xs[2] - mu2) / sg2, z3 = (xs[3] - mu3) / sg3;
        float e0 = ((-0.5f * z0) * z0 - ls0) - HL2PI;
        float e1 = ((-0.5f * z1) * z1 - ls1) - HL2PI;
        float e2 = ((-0.5f * z2) * z2 - ls2) - HL2PI;
        float e3 = ((-0.5f * z3) * z3 - ls3) - HL2PI;
        float dreg = (((e0 + e1) + e2) + e3) + lpi;
        pbuf[0][j] = dreg;
        dstore[(size_t)b * 64 + j] = dreg;          // row t=0
        cfence();

        // pipeline: emission for t=1
        float lpc;
        {
            int t6 = 6;
            float w0 = (xs[t6] - mu0) / sg0, w1 = (xs[t6 + 1] - mu1) / sg1;
            float w2 = (xs[t6 + 2] - mu2) / sg2, w3 = (xs[t6 + 3] - mu3) / sg3;
            float f0 = ((-0.5f * w0) * w0 - ls0) - HL2PI;
            float f1 = ((-0.5f * w1) * w1 - ls1) - HL2PI;
            float f2 = ((-0.5f * w2) * w2 - ls2) - HL2PI;
            float f3 = ((-0.5f * w3) * w3 - ls3) - HL2PI;
            lpc = ((f0 + f1) + f2) + f3;
        }

        int cur = 0;
#pragma unroll 1
        for (int t = 1; t < T_LEN; ++t) {
            float lpn = 0.f;
            if (t + 1 < T_LEN) {
                int t6 = (t + 1) * 6;
                float w0 = (xs[t6] - mu0) / sg0, w1 = (xs[t6 + 1] - mu1) / sg1;
                float w2 = (xs[t6 + 2] - mu2) / sg2, w3 = (xs[t6 + 3] - mu3) / sg3;
                float f0 = ((-0.5f * w0) * w0 - ls0) - HL2PI;
                float f1 = ((-0.5f * w1) * w1 - ls1) - HL2PI;
                float f2 = ((-0.5f * w2) * w2 - ls2) - HL2PI;
                float f3 = ((-0.5f * w3) * w3 - ls3) - HL2PI;
                lpn = ((f0 + f1) + f2) + f3;
            }

            const float4* dv = (const float4*)pbuf[cur];
            float m0 = -3.4e38f, m1 = -3.4e38f, m2 = -3.4e38f, m3 = -3.4e38f;
#pragma unroll
            for (int k = 0; k < 16; ++k) {
                float4 dd = dv[k];
                m0 = fmaxf(m0, dd.x + lA[4 * k + 0]);
                m1 = fmaxf(m1, dd.y + lA[4 * k + 1]);
                m2 = fmaxf(m2, dd.z + lA[4 * k + 2]);
                m3 = fmaxf(m3, dd.w + lA[4 * k + 3]);
            }
            float best = fmaxf(fmaxf(m0, m1), fmaxf(m2, m3));   // max assoc: bit-exact
            dreg = best + lpc;
            pbuf[cur ^ 1][j] = dreg;
            dstore[((size_t)t * B_SZ + b) * 64 + j] = dreg;
            cfence();
            cur ^= 1; lpc = lpn;
        }

        float vv = dreg; int idx = j;
        waveArgmax(vv, idx);
        if (j == 0) c_last[b] = idx;
    }
}

// ===== psi recompute: wave per (t,b), t in [1,2049] — round-1-verbatim argmax scan =====
extern "C" __global__ __launch_bounds__(256)
void hmm_psi(const float* __restrict__ dstore,
             const float* __restrict__ lAg,
             unsigned char* __restrict__ psi)
{
    __shared__ __align__(16) float sd[4][64];
    const int warp = threadIdx.x >> 6;
    const int j = threadIdx.x & 63;
    const int w = blockIdx.x * 4 + warp;          // 0 .. 262271
    const int t = (w >> 7) + 1;
    const int b = w & 127;

    float dval = dstore[((size_t)(t - 1) * B_SZ + b) * 64 + j];
    sd[warp][j] = dval;
    float lA[64];
    {
        const float4* g = (const float4*)lAg;
#pragma unroll
        for (int k = 0; k < 16; ++k) {
            float4 v = g[j * 16 + k];
            lA[4 * k + 0] = v.x; lA[4 * k + 1] = v.y;
            lA[4 * k + 2] = v.z; lA[4 * k + 3] = v.w;
        }
    }
    cfence();   // same-wave DS in-order

    const float4* dv = (const float4*)sd[warp];
    float bv0 = -3.4e38f, bv1 = -3.4e38f, bv2 = -3.4e38f, bv3 = -3.4e38f;
    int bi0 = 0, bi1 = 1, bi2 = 2, bi3 = 3;
#pragma unroll
    for (int k = 0; k < 16; ++k) {
        float4 dd = dv[k];
        float v0 = dd.x + lA[4 * k + 0];
        float v1 = dd.y + lA[4 * k + 1];
        float v2 = dd.z + lA[4 * k + 2];
        float v3 = dd.w + lA[4 * k + 3];
        if (v0 > bv0) { bv0 = v0; bi0 = 4 * k + 0; }
        if (v1 > bv1) { bv1 = v1; bi1 = 4 * k + 1; }
        if (v2 > bv2) { bv2 = v2; bi2 = 4 * k + 2; }
        if (v3 > bv3) { bv3 = v3; bi3 = 4 * k + 3; }
    }
    float best = bv0; int bidx = bi0;
    if (bv1 > best || (bv1 == best && bi1 < bidx)) { best = bv1; bidx = bi1; }
    if (bv2 > best || (bv2 == best && bi2 < bidx)) { best = bv2; bidx = bi2; }
    if (bv3 > best || (bv3 == best && bi3 < bidx)) { best = bv3; bidx = bi3; }

    psi[((size_t)t * B_SZ + b) * 64 + j] = (unsigned char)bidx;
}

// ===== per-chunk backpointer composition: wave per (b, g) =====
extern "C" __global__ __launch_bounds__(256)
void hmm_compose(const unsigned char* __restrict__ psi,
                 unsigned char* __restrict__ mt)
{
    const int w = blockIdx.x * 4 + (threadIdx.x >> 6);   // 0 .. 4223
    const int j = threadIdx.x & 63;
    const int g = w % NCHUNK;
    const int b = w / NCHUNK;
    const int e = (g < NCHUNK - 1) ? g * 64 + 64 : (T_LEN - 1);
    int M = j;
    for (int t = e; t >= g * 64 + 1; --t)
        M = psi[((size_t)t * B_SZ + b) * 64 + M];
    mt[((size_t)g * B_SZ + b) * 64 + j] = (unsigned char)M;
}

// ===== boundary walk + parallel chunk fill: block per batch =====
extern "C" __global__ __launch_bounds__(64, 1)
void hmm_fill(const unsigned char* __restrict__ psi,
              const unsigned char* __restrict__ mt,
              const int* __restrict__ c_last,
              float* __restrict__ out)
{
    __shared__ int sb[NCHUNK];       // sb[g] = state at t = 64*g
    const int b = blockIdx.x;
    const int g = threadIdx.x;
    const int cl = c_last[b];
    if (g == 0) {
        int cur = cl;
        for (int q = NCHUNK - 1; q >= 0; --q) {
            cur = mt[((size_t)q * B_SZ + b) * 64 + cur];
            sb[q] = cur;
        }
    }
    cfence();   // single wave, in-order DS
    float* oc = out + B_SZ + (size_t)b * T_LEN;
    if (g == NCHUNK) {
        oc[T_LEN - 1] = (float)cl;
    } else if (g < NCHUNK) {
        const int e = (g < NCHUNK - 1) ? g * 64 + 64 : (T_LEN - 1);
        int s = (g < NCHUNK - 1) ? sb[g + 1] : cl;
        for (int t = e; t >= g * 64 + 1; --t) {
            s = psi[((size_t)t * B_SZ + b) * 64 + s];
            oc[t - 1] = (float)s;
        }
    }
}

extern "C" void kernel_launch(void* const* d_in, const int* in_sizes, int n_in,
                              void* d_out, int out_size, void* d_ws, size_t ws_size,
                              hipStream_t stream)
{
    const float* x      = (const float*)d_in[0];
    const float* means  = (const float*)d_in[1];
    const float* stds   = (const float*)d_in[2];
    const float* logA   = (const float*)d_in[3];
    const float* logpi  = (const float*)d_in[4];
    float* out = (float*)d_out;

    // workspace layout (need 84,255,488 B; round-2 behavior proved ws >= 85,022,208 B)
    char* base = (char*)d_ws;
    float*         dstore = (float*)base;                                  // 67,174,400
    unsigned char* psi    = (unsigned char*)(base + 67174400);             // 16,793,600
    unsigned char* mt     = (unsigned char*)(base + 83968000);             //    270,336
    int*           cl     = (int*)(base + 84238336);                       //        512
    float*         lAg    = (float*)(base + 84238848);                     //     16,384
    float*         lpig   = (float*)(base + 84255232);                     //        256

    hipLaunchKernelGGL(hmm_prep, dim3(1), dim3(64), 0, stream, logA, logpi, lAg, lpig);
    hipLaunchKernelGGL(hmm_main, dim3(2 * B_SZ), dim3(64), 0, stream,
                       x, means, stds, lAg, lpig, out, dstore, cl);
    hipLaunchKernelGGL(hmm_psi, dim3((2049 * B_SZ) / 4), dim3(256), 0, stream,
                       dstore, lAg, psi);
    hipLaunchKernelGGL(hmm_compose, dim3((NCHUNK * B_SZ) / 4), dim3(256), 0, stream, psi, mt);
    hipLaunchKernelGGL(hmm_fill, dim3(B_SZ), dim3(64), 0, stream, psi, mt, cl, out);
}

// Round 6
// 1426.317 us; speedup vs baseline: 8.8148x; 1.2087x over previous
//
#include <hip/hip_runtime.h>

#define T_LEN 2050
#define B_SZ 128
#define NCHUNK 33               // chunks of steps t=1..2049
#define HL2PI 0.91893853320467274178f

// ---------- wave-wide helpers (wave = 64 lanes) ----------
__device__ __forceinline__ float waveMax(float v) {
#pragma unroll
    for (int off = 32; off >= 1; off >>= 1)
        v = fmaxf(v, __shfl_xor(v, off, 64));
    return v;
}
__device__ __forceinline__ float waveSum(float v) {
#pragma unroll
    for (int off = 32; off >= 1; off >>= 1)
        v += __shfl_xor(v, off, 64);
    return v;
}
__device__ __forceinline__ void waveArgmax(float& v, int& idx) {
#pragma unroll
    for (int off = 32; off >= 1; off >>= 1) {
        float ov = __shfl_xor(v, off, 64);
        int   oi = __shfl_xor(idx, off, 64);
        if (ov > v || (ov == v && oi < idx)) { v = ov; idx = oi; }
    }
}
__device__ __forceinline__ void cfence() { asm volatile("" ::: "memory"); }
// LDS-publishing barrier that does NOT drain vmcnt (CK block_sync_lds pattern):
// global stores (psi) stay in flight across steps.
__device__ __forceinline__ void wgbar() {
    asm volatile("s_waitcnt lgkmcnt(0)\n\ts_barrier" ::: "memory");
}

// DPP full-wave reductions (round-5 proven)
__device__ __forceinline__ float dppSumAll(float v) {
#define SSTEP(ctrl) { int t_ = __builtin_amdgcn_update_dpp(0, __float_as_int(v), ctrl, 0xf, 0xf, true); \
                      v = v + __int_as_float(t_); }
    SSTEP(0x111) SSTEP(0x112) SSTEP(0x114) SSTEP(0x118) SSTEP(0x142) SSTEP(0x143)
#undef SSTEP
    return __int_as_float(__builtin_amdgcn_readlane(__float_as_int(v), 63));
}
__device__ __forceinline__ float dppMaxAll(float v) {
#define MSTEP(ctrl) { int t_ = __builtin_amdgcn_update_dpp(__float_as_int(v), __float_as_int(v), ctrl, 0xf, 0xf, false); \
                      v = fmaxf(v, __int_as_float(t_)); }
    MSTEP(0x111) MSTEP(0x112) MSTEP(0x114) MSTEP(0x118) MSTEP(0x142) MSTEP(0x143)
#undef MSTEP
    return __int_as_float(__builtin_amdgcn_readlane(__float_as_int(v), 63));
}

// ===== prep: log_softmax(log_A) -> lAg[c*64+i] (column-major), log_softmax(log_pi) =====
extern "C" __global__ __launch_bounds__(64, 1)
void hmm_prep(const float* __restrict__ logA_in,
              const float* __restrict__ logpi_in,
              float* __restrict__ lAg,
              float* __restrict__ lpig)
{
    __shared__ float la[64 * 65];
    __shared__ float rowlse[64];
    const int j = threadIdx.x;
#pragma unroll
    for (int k = 0; k < 64; ++k)
        la[k * 65 + j] = logA_in[k * 64 + j];
    cfence();
    {   // exact op order (round-1..5 proven)
        float m = -1e30f;
#pragma unroll
        for (int k = 0; k < 64; ++k) m = fmaxf(m, la[j * 65 + k]);
        float s = 0.f;
#pragma unroll
        for (int k = 0; k < 64; ++k) s += expf(la[j * 65 + k] - m);
        rowlse[j] = m + logf(s);
    }
    cfence();
    {
        float v = logpi_in[j];
        float m = waveMax(v);
        float s = waveSum(expf(v - m));
        lpig[j] = v - (m + logf(s));
    }
    float4* o = (float4*)lAg;
#pragma unroll
    for (int k = 0; k < 16; ++k) {
        float4 v;
        v.x = la[(4 * k + 0) * 65 + j] - rowlse[4 * k + 0];
        v.y = la[(4 * k + 1) * 65 + j] - rowlse[4 * k + 1];
        v.z = la[(4 * k + 2) * 65 + j] - rowlse[4 * k + 2];
        v.w = la[(4 * k + 3) * 65 + j] - rowlse[4 * k + 3];
        o[j * 16 + k] = v;
    }
}

// ===== main: 4 waves/block cooperate on one chain.
// blocks 0..127: forward -> out[b]; blocks 128..255: viterbi -> psi, c_last =====
extern "C" __global__ __launch_bounds__(256, 1)
void hmm_main(const float* __restrict__ x,
              const float* __restrict__ means,
              const float* __restrict__ stds,
              const float* __restrict__ lAg,
              const float* __restrict__ lpig,
              float* __restrict__ out,
              unsigned char* __restrict__ psi,
              int* __restrict__ c_last)
{
    __shared__ __align__(16) float xs[12304];       // x[b]: [t*6+d]
    __shared__ __align__(16) float pbuf[2][64];     // u (fwd) / d (vit), dbl-buffered
    __shared__ float mbuf[2][4];                    // per-wave lp-max partials (pipelined)
    __shared__ float sbuf[2][4];                    // per-wave u-sum partials

    const int tid = threadIdx.x;
    const int w   = tid >> 6;          // wave 0..3
    const int l   = tid & 63;          // lane
    const int g   = l >> 4;            // i-segment id 0..3
    const int c   = w * 16 + (l & 15); // my column (output state)
    const int bid = blockIdx.x;
    const bool is_fwd = (bid < B_SZ);
    const int b = is_fwd ? bid : bid - B_SZ;

    // stage x cooperatively (coalesced float4)
    {
        const float4* xg4 = (const float4*)(x + (size_t)b * T_LEN * 6);
        float4* xs4 = (float4*)xs;
        for (int i = tid; i < 3075; i += 256) xs4[i] = xg4[i];
    }

    // per-column emission constants (state c)
    float mu0 = means[c * 6 + 0], mu1 = means[c * 6 + 1];
    float mu2 = means[c * 6 + 2], mu3 = means[c * 6 + 3];
    float sg0 = fmaxf(stds[c * 6 + 0], 0.f) + 0.1f;
    float sg1 = fmaxf(stds[c * 6 + 1], 0.f) + 0.1f;
    float sg2 = fmaxf(stds[c * 6 + 2], 0.f) + 0.1f;
    float sg3 = fmaxf(stds[c * 6 + 3], 0.f) + 0.1f;
    float ls0 = logf(sg0), ls1 = logf(sg1), ls2 = logf(sg2), ls3 = logf(sg3);
    float lpi_c = lpig[c];

    __syncthreads();   // once at init (xs published; vmcnt drain harmless here)

    if (is_fwd) {
        // ---------------- FORWARD (prob space, deferred rescale; round-5 math) ----------------
        float Ac[16];      // A[i][c] for i in my segment
        {
            const float4* gA = (const float4*)(lAg + (size_t)c * 64 + g * 16);
#pragma unroll
            for (int k = 0; k < 4; ++k) {
                float4 v = gA[k];
                Ac[4 * k + 0] = __expf(v.x); Ac[4 * k + 1] = __expf(v.y);
                Ac[4 * k + 2] = __expf(v.z); Ac[4 * k + 3] = __expf(v.w);
            }
        }
        float i0 = 1.f / sg0, i1 = 1.f / sg1, i2 = 1.f / sg2, i3 = 1.f / sg3;
        float cst = -(ls0 + ls1 + ls2 + ls3) - 4.f * HL2PI;

        // ---- t = 0 prologue ----
        float z0 = (xs[0] - mu0) * i0, z1 = (xs[1] - mu1) * i1;
        float z2 = (xs[2] - mu2) * i2, z3 = (xs[3] - mu3) * i3;
        float a0 = (cst - 0.5f * (z0 * z0 + z1 * z1 + z2 * z2 + z3 * z3)) + lpi_c;
        float wm = dppMaxAll(a0);             // max over my wave's 16 cols (copies harmless)
        if (l == 0) mbuf[0][w] = wm;
        wgbar();
        float mm = fmaxf(fmaxf(mbuf[0][0], mbuf[0][1]), fmaxf(mbuf[0][2], mbuf[0][3]));
        float u0 = __expf(a0 - mm);
        if (g == 0) pbuf[0][c] = u0;
        float ps = dppSumAll(u0) * 0.25f;     // 4 copies summed -> scale back (exact pow2)
        if (l == 0) sbuf[0][w] = ps;
        // pipeline emission for t=1
        float lp_c;
        {
            float y0 = (xs[6] - mu0) * i0, y1 = (xs[7] - mu1) * i1;
            float y2 = (xs[8] - mu2) * i2, y3 = (xs[9] - mu3) * i3;
            lp_c = cst - 0.5f * (y0 * y0 + y1 * y1 + y2 * y2 + y3 * y3);
        }
        float wmn = dppMaxAll(lp_c);
        if (l == 0) mbuf[1][w] = wmn;
        float mm_prev = mm;
        double acc = 0.0;
        wgbar();    // publish pbuf[0], sbuf[0], mbuf[1]

#pragma unroll 1
        for (int t = 1; t < T_LEN; ++t) {
            const int rs = (t - 1) & 1, wsl = t & 1;
            // gather my u segment (same-address float4 broadcast across 16 lanes)
            const float4* uv = (const float4*)(pbuf[rs] + g * 16);
            float4 ua = uv[0], ub = uv[1], uc = uv[2], ud = uv[3];
            float mmc = fmaxf(fmaxf(mbuf[wsl][0], mbuf[wsl][1]), fmaxf(mbuf[wsl][2], mbuf[wsl][3]));
            float sp = ((sbuf[rs][0] + sbuf[rs][1]) + sbuf[rs][2]) + sbuf[rs][3];
            float rcp = 1.0f / sp;
            acc += (double)(mm_prev + __logf(sp));

            float qp = 0.f;
            qp = fmaf(ua.x, Ac[0], qp);  qp = fmaf(ua.y, Ac[1], qp);
            qp = fmaf(ua.z, Ac[2], qp);  qp = fmaf(ua.w, Ac[3], qp);
            qp = fmaf(ub.x, Ac[4], qp);  qp = fmaf(ub.y, Ac[5], qp);
            qp = fmaf(ub.z, Ac[6], qp);  qp = fmaf(ub.w, Ac[7], qp);
            qp = fmaf(uc.x, Ac[8], qp);  qp = fmaf(uc.y, Ac[9], qp);
            qp = fmaf(uc.z, Ac[10], qp); qp = fmaf(uc.w, Ac[11], qp);
            qp = fmaf(ud.x, Ac[12], qp); qp = fmaf(ud.y, Ac[13], qp);
            qp = fmaf(ud.z, Ac[14], qp); qp = fmaf(ud.w, Ac[15], qp);
            qp += __shfl_xor(qp, 16, 64);          // commutative: same bits all copies
            qp += __shfl_xor(qp, 32, 64);

            float e = __expf(lp_c - mmc) * rcp;
            float un = qp * e;
            if (g == 0) pbuf[wsl][c] = un;
            float psn = dppSumAll(un) * 0.25f;
            if (l == 0) sbuf[wsl][w] = psn;

            // pipeline emission for t+1
            int tn6 = (t + 1 < T_LEN) ? (t + 1) * 6 : t * 6;
            float y0 = (xs[tn6] - mu0) * i0, y1 = (xs[tn6 + 1] - mu1) * i1;
            float y2 = (xs[tn6 + 2] - mu2) * i2, y3 = (xs[tn6 + 3] - mu3) * i3;
            float lpn = cst - 0.5f * (y0 * y0 + y1 * y1 + y2 * y2 + y3 * y3);
            float wm2 = dppMaxAll(lpn);
            if (l == 0) mbuf[(t + 1) & 1][w] = wm2;

            wgbar();
            lp_c = lpn; mm_prev = mmc;
        }
        // last scaler: s_2049 partials published by final wgbar
        float spl = ((sbuf[1][0] + sbuf[1][1]) + sbuf[1][2]) + sbuf[1][3];
        acc += (double)(mm_prev + __logf(spl));
        if (tid == 0) out[b] = (float)acc;
    } else {
        // ---------------- VITERBI (bit-faithful, inline argmax) ----------------
        float lA[16];      // log_A[i][c] for i in my segment
        {
            const float4* gA = (const float4*)(lAg + (size_t)c * 64 + g * 16);
#pragma unroll
            for (int k = 0; k < 4; ++k) {
                float4 v = gA[k];
                lA[4 * k + 0] = v.x; lA[4 * k + 1] = v.y;
                lA[4 * k + 2] = v.z; lA[4 * k + 3] = v.w;
            }
        }
        // t = 0 (exact reference op order, divisions)
        float z0 = (xs[0] - mu0) / sg0, z1 = (xs[1] - mu1) / sg1;
        float z2 = (xs[2] - mu2) / sg2, z3 = (xs[3] - mu3) / sg3;
        float e0 = ((-0.5f * z0) * z0 - ls0) - HL2PI;
        float e1 = ((-0.5f * z1) * z1 - ls1) - HL2PI;
        float e2 = ((-0.5f * z2) * z2 - ls2) - HL2PI;
        float e3 = ((-0.5f * z3) * z3 - ls3) - HL2PI;
        float d0v = (((e0 + e1) + e2) + e3) + lpi_c;
        if (g == 0) pbuf[0][c] = d0v;
        // pipeline emission for t=1 (exact)
        float lp_c;
        {
            float y0 = (xs[6] - mu0) / sg0, y1 = (xs[7] - mu1) / sg1;
            float y2 = (xs[8] - mu2) / sg2, y3 = (xs[9] - mu3) / sg3;
            float f0 = ((-0.5f * y0) * y0 - ls0) - HL2PI;
            float f1 = ((-0.5f * y1) * y1 - ls1) - HL2PI;
            float f2 = ((-0.5f * y2) * y2 - ls2) - HL2PI;
            float f3 = ((-0.5f * y3) * y3 - ls3) - HL2PI;
            lp_c = ((f0 + f1) + f2) + f3;
        }
        wgbar();

        unsigned char* pp = psi + ((size_t)B_SZ + b) * 64 + c;   // row t=1
#pragma unroll 1
        for (int t = 1; t < T_LEN; ++t) {
            const int rs = (t - 1) & 1, wsl = t & 1;
            const float4* dv = (const float4*)(pbuf[rs] + g * 16);
            float4 da = dv[0], db = dv[1], dc4 = dv[2], dd = dv[3];

            // ascending-i tracker over my 16 (strict > keeps first occurrence)
            float bv = da.x + lA[0]; int bi = 0; float v;
            v = da.y + lA[1];  if (v > bv) { bv = v; bi = 1; }
            v = da.z + lA[2];  if (v > bv) { bv = v; bi = 2; }
            v = da.w + lA[3];  if (v > bv) { bv = v; bi = 3; }
            v = db.x + lA[4];  if (v > bv) { bv = v; bi = 4; }
            v = db.y + lA[5];  if (v > bv) { bv = v; bi = 5; }
            v = db.z + lA[6];  if (v > bv) { bv = v; bi = 6; }
            v = db.w + lA[7];  if (v > bv) { bv = v; bi = 7; }
            v = dc4.x + lA[8]; if (v > bv) { bv = v; bi = 8; }
            v = dc4.y + lA[9]; if (v > bv) { bv = v; bi = 9; }
            v = dc4.z + lA[10]; if (v > bv) { bv = v; bi = 10; }
            v = dc4.w + lA[11]; if (v > bv) { bv = v; bi = 11; }
            v = dd.x + lA[12]; if (v > bv) { bv = v; bi = 12; }
            v = dd.y + lA[13]; if (v > bv) { bv = v; bi = 13; }
            v = dd.z + lA[14]; if (v > bv) { bv = v; bi = 14; }
            v = dd.w + lA[15]; if (v > bv) { bv = v; bi = 15; }
            bi += g * 16;

            // cross-segment merges (tie -> lower index == np.argmax first-occurrence)
            float ov = __shfl_xor(bv, 16, 64); int oi = __shfl_xor(bi, 16, 64);
            if (ov > bv || (ov == bv && oi < bi)) { bv = ov; bi = oi; }
            ov = __shfl_xor(bv, 32, 64); oi = __shfl_xor(bi, 32, 64);
            if (ov > bv || (ov == bv && oi < bi)) { bv = ov; bi = oi; }

            float dn = bv + lp_c;
            if (g == 0) {
                pbuf[wsl][c] = dn;
                *pp = (unsigned char)bi;     // global store; NOT drained by wgbar
            }
            pp += B_SZ * 64;

            // pipeline emission for t+1 (exact)
            int tn6 = (t + 1 < T_LEN) ? (t + 1) * 6 : t * 6;
            float y0 = (xs[tn6] - mu0) / sg0, y1 = (xs[tn6 + 1] - mu1) / sg1;
            float y2 = (xs[tn6 + 2] - mu2) / sg2, y3 = (xs[tn6 + 3] - mu3) / sg3;
            float f0 = ((-0.5f * y0) * y0 - ls0) - HL2PI;
            float f1 = ((-0.5f * y1) * y1 - ls1) - HL2PI;
            float f2 = ((-0.5f * y2) * y2 - ls2) - HL2PI;
            float f3 = ((-0.5f * y3) * y3 - ls3) - HL2PI;
            float lpn = ((f0 + f1) + f2) + f3;

            wgbar();
            lp_c = lpn;
        }

        // c_last: argmax over final d (pbuf[1], t=2049) with first-occurrence
        float vv = pbuf[1][l]; int idx = l;
        waveArgmax(vv, idx);
        if (tid == 0) c_last[b] = idx;
    }
}

// ===== per-chunk backpointer composition: wave per (b, g) =====
extern "C" __global__ __launch_bounds__(256)
void hmm_compose(const unsigned char* __restrict__ psi,
                 unsigned char* __restrict__ mt)
{
    const int w = blockIdx.x * 4 + (threadIdx.x >> 6);   // 0 .. 4223
    const int j = threadIdx.x & 63;
    const int g = w % NCHUNK;
    const int b = w / NCHUNK;
    const int e = (g < NCHUNK - 1) ? g * 64 + 64 : (T_LEN - 1);
    int M = j;
    for (int t = e; t >= g * 64 + 1; --t)
        M = psi[((size_t)t * B_SZ + b) * 64 + M];
    mt[((size_t)g * B_SZ + b) * 64 + j] = (unsigned char)M;
}

// ===== boundary walk + parallel chunk fill: block per batch =====
extern "C" __global__ __launch_bounds__(64, 1)
void hmm_fill(const unsigned char* __restrict__ psi,
              const unsigned char* __restrict__ mt,
              const int* __restrict__ c_last,
              float* __restrict__ out)
{
    __shared__ int sb[NCHUNK];       // sb[g] = state at t = 64*g
    const int b = blockIdx.x;
    const int g = threadIdx.x;
    const int cl = c_last[b];
    if (g == 0) {
        int cur = cl;
        for (int q = NCHUNK - 1; q >= 0; --q) {
            cur = mt[((size_t)q * B_SZ + b) * 64 + cur];
            sb[q] = cur;
        }
    }
    cfence();   // single wave, in-order DS
    float* oc = out + B_SZ + (size_t)b * T_LEN;
    if (g == NCHUNK) {
        oc[T_LEN - 1] = (float)cl;
    } else if (g < NCHUNK) {
        const int e = (g < NCHUNK - 1) ? g * 64 + 64 : (T_LEN - 1);
        int s = (g < NCHUNK - 1) ? sb[g + 1] : cl;
        for (int t = e; t >= g * 64 + 1; --t) {
            s = psi[((size_t)t * B_SZ + b) * 64 + s];
            oc[t - 1] = (float)s;
        }
    }
}

extern "C" void kernel_launch(void* const* d_in, const int* in_sizes, int n_in,
                              void* d_out, int out_size, void* d_ws, size_t ws_size,
                              hipStream_t stream)
{
    const float* x      = (const float*)d_in[0];
    const float* means  = (const float*)d_in[1];
    const float* stds   = (const float*)d_in[2];
    const float* logA   = (const float*)d_in[3];
    const float* logpi  = (const float*)d_in[4];
    float* out = (float*)d_out;

    // workspace layout (~17.1 MB)
    char* base = (char*)d_ws;
    unsigned char* psi  = (unsigned char*)base;                 // 16,793,600
    unsigned char* mt   = (unsigned char*)(base + 16793600);    //    270,336
    int*           cl   = (int*)(base + 17063936);              //        512
    float*         lAg  = (float*)(base + 17064448);            //     16,384
    float*         lpig = (float*)(base + 17080832);            //        256

    hipLaunchKernelGGL(hmm_prep, dim3(1), dim3(64), 0, stream, logA, logpi, lAg, lpig);
    hipLaunchKernelGGL(hmm_main, dim3(2 * B_SZ), dim3(256), 0, stream,
                       x, means, stds, lAg, lpig, out, psi, cl);
    hipLaunchKernelGGL(hmm_compose, dim3((NCHUNK * B_SZ) / 4), dim3(256), 0, stream, psi, mt);
    hipLaunchKernelGGL(hmm_fill, dim3(B_SZ), dim3(64), 0, stream, psi, mt, cl, out);
}

// Round 7
// 1077.790 us; speedup vs baseline: 11.6653x; 1.3234x over previous
//
#include <hip/hip_runtime.h>

#define T_LEN 2050
#define B_SZ 128
#define NCHUNK 33               // chunks of steps t=1..2049
#define HL2PI 0.91893853320467274178f

// ---------- wave-wide helpers (wave = 64 lanes) ----------
__device__ __forceinline__ float waveMax(float v) {
#pragma unroll
    for (int off = 32; off >= 1; off >>= 1)
        v = fmaxf(v, __shfl_xor(v, off, 64));
    return v;
}
__device__ __forceinline__ float waveSum(float v) {
#pragma unroll
    for (int off = 32; off >= 1; off >>= 1)
        v += __shfl_xor(v, off, 64);
    return v;
}
__device__ __forceinline__ void waveArgmax(float& v, int& idx) {
#pragma unroll
    for (int off = 32; off >= 1; off >>= 1) {
        float ov = __shfl_xor(v, off, 64);
        int   oi = __shfl_xor(idx, off, 64);
        if (ov > v || (ov == v && oi < idx)) { v = ov; idx = oi; }
    }
}
__device__ __forceinline__ void cfence() { asm volatile("" ::: "memory"); }

// DPP full-wave reductions (round-5/6 proven)
__device__ __forceinline__ float dppSumAll(float v) {
#define SSTEP(ctrl) { int t_ = __builtin_amdgcn_update_dpp(0, __float_as_int(v), ctrl, 0xf, 0xf, true); \
                      v = v + __int_as_float(t_); }
    SSTEP(0x111) SSTEP(0x112) SSTEP(0x114) SSTEP(0x118) SSTEP(0x142) SSTEP(0x143)
#undef SSTEP
    return __int_as_float(__builtin_amdgcn_readlane(__float_as_int(v), 63));
}
__device__ __forceinline__ float dppMaxAll(float v) {
#define MSTEP(ctrl) { int t_ = __builtin_amdgcn_update_dpp(__float_as_int(v), __float_as_int(v), ctrl, 0xf, 0xf, false); \
                      v = fmaxf(v, __int_as_float(t_)); }
    MSTEP(0x111) MSTEP(0x112) MSTEP(0x114) MSTEP(0x118) MSTEP(0x142) MSTEP(0x143)
#undef MSTEP
    return __int_as_float(__builtin_amdgcn_readlane(__float_as_int(v), 63));
}

// ===== prep: log_softmax(log_A) -> lAg[c*64+i] (column-major), log_softmax(log_pi) =====
extern "C" __global__ __launch_bounds__(64, 1)
void hmm_prep(const float* __restrict__ logA_in,
              const float* __restrict__ logpi_in,
              float* __restrict__ lAg,
              float* __restrict__ lpig)
{
    __shared__ float la[64 * 65];
    __shared__ float rowlse[64];
    const int j = threadIdx.x;
#pragma unroll
    for (int k = 0; k < 64; ++k)
        la[k * 65 + j] = logA_in[k * 64 + j];
    cfence();
    {   // exact op order (rounds 1..6 proven)
        float m = -1e30f;
#pragma unroll
        for (int k = 0; k < 64; ++k) m = fmaxf(m, la[j * 65 + k]);
        float s = 0.f;
#pragma unroll
        for (int k = 0; k < 64; ++k) s += expf(la[j * 65 + k] - m);
        rowlse[j] = m + logf(s);
    }
    cfence();
    {
        float v = logpi_in[j];
        float m = waveMax(v);
        float s = waveSum(expf(v - m));
        lpig[j] = v - (m + logf(s));
    }
    float4* o = (float4*)lAg;
#pragma unroll
    for (int k = 0; k < 16; ++k) {
        float4 v;
        v.x = la[(4 * k + 0) * 65 + j] - rowlse[4 * k + 0];
        v.y = la[(4 * k + 1) * 65 + j] - rowlse[4 * k + 1];
        v.z = la[(4 * k + 2) * 65 + j] - rowlse[4 * k + 2];
        v.w = la[(4 * k + 3) * 65 + j] - rowlse[4 * k + 3];
        o[j * 16 + k] = v;
    }
}

// ===== main: single wave per chain, software-pipelined, fence-free.
// blocks 0..127: forward -> out[b]; blocks 128..255: viterbi (values-only) -> dstore, c_last =====
extern "C" __global__ __launch_bounds__(64, 1)
void hmm_main(const float* __restrict__ x,
              const float* __restrict__ means,
              const float* __restrict__ stds,
              const float* __restrict__ lAg,
              const float* __restrict__ lpig,
              float* __restrict__ out,
              float* __restrict__ dstore,
              int* __restrict__ c_last)
{
    __shared__ __align__(16) float xs[12304];     // x[b]: [t*6+d]
    __shared__ __align__(16) float pbuf[64];      // single buffer: write-then-readback

    const int j   = threadIdx.x;
    const int bid = blockIdx.x;
    const bool is_fwd = (bid < B_SZ);
    const int b = is_fwd ? bid : bid - B_SZ;

    // stage x (coalesced float4; same-wave in-order DS => later reads see it)
    {
        const float4* xg4 = (const float4*)(x + (size_t)b * T_LEN * 6);
        float4* xs4 = (float4*)xs;
        for (int i = j; i < 3075; i += 64) xs4[i] = xg4[i];
    }
    float lpi = lpig[j];

    // per-state emission constants
    float mu0 = means[j * 6 + 0], mu1 = means[j * 6 + 1];
    float mu2 = means[j * 6 + 2], mu3 = means[j * 6 + 3];
    float sg0 = fmaxf(stds[j * 6 + 0], 0.f) + 0.1f;
    float sg1 = fmaxf(stds[j * 6 + 1], 0.f) + 0.1f;
    float sg2 = fmaxf(stds[j * 6 + 2], 0.f) + 0.1f;
    float sg3 = fmaxf(stds[j * 6 + 3], 0.f) + 0.1f;
    float ls0 = logf(sg0), ls1 = logf(sg1), ls2 = logf(sg2), ls3 = logf(sg3);

    const float4* pv = (const float4*)pbuf;

    if (is_fwd) {
        // ---------------- FORWARD (prob space, deferred rescale; round-5 math) ----------------
        float Ac[64];
        {
            const float4* g = (const float4*)lAg;
#pragma unroll
            for (int k = 0; k < 16; ++k) {
                float4 v = g[j * 16 + k];
                Ac[4 * k + 0] = __expf(v.x); Ac[4 * k + 1] = __expf(v.y);
                Ac[4 * k + 2] = __expf(v.z); Ac[4 * k + 3] = __expf(v.w);
            }
        }
        float i0 = 1.f / sg0, i1 = 1.f / sg1, i2 = 1.f / sg2, i3 = 1.f / sg3;
        float cst = -(ls0 + ls1 + ls2 + ls3) - 4.f * HL2PI;

        // ---- prologue: t = 0 ----
        float z0 = (xs[0] - mu0) * i0, z1 = (xs[1] - mu1) * i1;
        float z2 = (xs[2] - mu2) * i2, z3 = (xs[3] - mu3) * i3;
        float a0 = (cst - 0.5f * (z0 * z0 + z1 * z1 + z2 * z2 + z3 * z3)) + lpi;
        float mm0 = dppMaxAll(a0);
        float u0 = __expf(a0 - mm0);
        pbuf[j] = u0;
        float4 rr[16];
#pragma unroll
        for (int k = 0; k < 16; ++k) rr[k] = pv[k];
        float s0 = dppSumAll(u0);
        double acc = (double)(mm0 + __logf(s0));
        float rcp = 1.0f / s0;
        // emission for t = 1
        float lp1;
        {
            float y0 = (xs[6] - mu0) * i0, y1 = (xs[7] - mu1) * i1;
            float y2 = (xs[8] - mu2) * i2, y3 = (xs[9] - mu3) * i3;
            lp1 = cst - 0.5f * (y0 * y0 + y1 * y1 + y2 * y2 + y3 * y3);
        }
        float mm_c = dppMaxAll(lp1);
        float e_c  = __expf(lp1 - mm_c) * rcp;

#pragma unroll 1
        for (int t = 1; t < T_LEN; ++t) {
            // issue next emission's xs reads FIRST (drain during reduce)
            int o = ((t + 1 < T_LEN) ? (t + 1) : t) * 6;
            float y0 = xs[o], y1 = xs[o + 1], y2 = xs[o + 2], y3 = xs[o + 3];

            // reduce: q = sum_i u[i] * A[i][j]
            float q0 = 0.f, q1 = 0.f, q2 = 0.f, q3 = 0.f;
#pragma unroll
            for (int k = 0; k < 16; ++k) {
                float4 pp = rr[k];
                q0 = fmaf(pp.x, Ac[4 * k + 0], q0);
                q1 = fmaf(pp.y, Ac[4 * k + 1], q1);
                q2 = fmaf(pp.z, Ac[4 * k + 2], q2);
                q3 = fmaf(pp.w, Ac[4 * k + 3], q3);
            }
            float q = (q0 + q1) + (q2 + q3);
            float u = q * e_c;

            // publish + readback immediately (in-order same-wave LDS)
            pbuf[j] = u;
#pragma unroll
            for (int k = 0; k < 16; ++k) rr[k] = pv[k];

            // overlap-with-flight work:
            float s = dppSumAll(u);
            acc += (double)(mm_c + __logf(s));
            rcp = 1.0f / s;
            float w0 = (y0 - mu0) * i0, w1 = (y1 - mu1) * i1;
            float w2 = (y2 - mu2) * i2, w3 = (y3 - mu3) * i3;
            float lpn = cst - 0.5f * (w0 * w0 + w1 * w1 + w2 * w2 + w3 * w3);
            float mmn = dppMaxAll(lpn);
            e_c  = __expf(lpn - mmn) * rcp;
            mm_c = mmn;
        }
        if (j == 0) out[b] = (float)acc;
    } else {
        // ---------------- VITERBI: values-only (max associative => bit-exact), d -> dstore ----------------
        float lA[64];
        {
            const float4* g = (const float4*)lAg;
#pragma unroll
            for (int k = 0; k < 16; ++k) {
                float4 v = g[j * 16 + k];
                lA[4 * k + 0] = v.x; lA[4 * k + 1] = v.y;
                lA[4 * k + 2] = v.z; lA[4 * k + 3] = v.w;
            }
        }
        // ---- prologue: t = 0 (exact reference op order) ----
        float z0 = (xs[0] - mu0) / sg0, z1 = (xs[1] - mu1) / sg1;
        float z2 = (xs[2] - mu2) / sg2, z3 = (xs[3] - mu3) / sg3;
        float e0 = ((-0.5f * z0) * z0 - ls0) - HL2PI;
        float e1 = ((-0.5f * z1) * z1 - ls1) - HL2PI;
        float e2 = ((-0.5f * z2) * z2 - ls2) - HL2PI;
        float e3 = ((-0.5f * z3) * z3 - ls3) - HL2PI;
        float dn = (((e0 + e1) + e2) + e3) + lpi;
        pbuf[j] = dn;
        float4 rr[16];
#pragma unroll
        for (int k = 0; k < 16; ++k) rr[k] = pv[k];
        float* dp = dstore + (size_t)b * 64 + j;      // row t=0
        *dp = dn;
        // emission for t = 1 (exact divisions)
        float lp_c;
        {
            float y0 = (xs[6] - mu0) / sg0, y1 = (xs[7] - mu1) / sg1;
            float y2 = (xs[8] - mu2) / sg2, y3 = (xs[9] - mu3) / sg3;
            float f0 = ((-0.5f * y0) * y0 - ls0) - HL2PI;
            float f1 = ((-0.5f * y1) * y1 - ls1) - HL2PI;
            float f2 = ((-0.5f * y2) * y2 - ls2) - HL2PI;
            float f3 = ((-0.5f * y3) * y3 - ls3) - HL2PI;
            lp_c = ((f0 + f1) + f2) + f3;
        }

#pragma unroll 1
        for (int t = 1; t < T_LEN; ++t) {
            // issue next emission's xs reads first
            int o = ((t + 1 < T_LEN) ? (t + 1) : t) * 6;
            float y0 = xs[o], y1 = xs[o + 1], y2 = xs[o + 2], y3 = xs[o + 3];

            // reduce: best = max_i(d[i] + lA[i][j])  (4 independent fmax chains)
            float m0 = -3.4e38f, m1 = -3.4e38f, m2 = -3.4e38f, m3 = -3.4e38f;
#pragma unroll
            for (int k = 0; k < 16; ++k) {
                float4 dd = rr[k];
                m0 = fmaxf(m0, dd.x + lA[4 * k + 0]);
                m1 = fmaxf(m1, dd.y + lA[4 * k + 1]);
                m2 = fmaxf(m2, dd.z + lA[4 * k + 2]);
                m3 = fmaxf(m3, dd.w + lA[4 * k + 3]);
            }
            float best = fmaxf(fmaxf(m0, m1), fmaxf(m2, m3));
            dn = best + lp_c;

            // publish + readback immediately
            pbuf[j] = dn;
#pragma unroll
            for (int k = 0; k < 16; ++k) rr[k] = pv[k];

            // overlap-with-flight work: global store + next emission (divides)
            dp += B_SZ * 64;
            *dp = dn;                                   // d_t row (fire-and-forget)
            float w0 = (y0 - mu0) / sg0, w1 = (y1 - mu1) / sg1;
            float w2 = (y2 - mu2) / sg2, w3 = (y3 - mu3) / sg3;
            float f0 = ((-0.5f * w0) * w0 - ls0) - HL2PI;
            float f1 = ((-0.5f * w1) * w1 - ls1) - HL2PI;
            float f2 = ((-0.5f * w2) * w2 - ls2) - HL2PI;
            float f3 = ((-0.5f * w3) * w3 - ls3) - HL2PI;
            lp_c = ((f0 + f1) + f2) + f3;
        }

        float vv = dn; int idx = j;
        waveArgmax(vv, idx);
        if (j == 0) c_last[b] = idx;
    }
}

// ===== psi recompute: persistent lA in regs, grid-stride over (t,b) pairs =====
extern "C" __global__ __launch_bounds__(256)
void hmm_psi(const float* __restrict__ dstore,
             const float* __restrict__ lAg,
             unsigned char* __restrict__ psi)
{
    __shared__ __align__(16) float sd[4][64];
    const int warp = threadIdx.x >> 6;
    const int j = threadIdx.x & 63;
    const int wid = blockIdx.x * 4 + warp;        // 0..2047

    float lA[64];
    {
        const float4* g = (const float4*)lAg;
#pragma unroll
        for (int k = 0; k < 16; ++k) {
            float4 v = g[j * 16 + k];
            lA[4 * k + 0] = v.x; lA[4 * k + 1] = v.y;
            lA[4 * k + 2] = v.z; lA[4 * k + 3] = v.w;
        }
    }
    const float4* dv = (const float4*)sd[warp];
    const int NP = 2049 * B_SZ;

    for (int p = wid; p < NP; p += 2048) {
        const int t = (p >> 7) + 1;
        const int b = p & 127;
        float dval = dstore[((size_t)(t - 1) * B_SZ + b) * 64 + j];
        sd[warp][j] = dval;    // same-wave in-order: reads below see it

        // round-5-verbatim argmax tracker (np.argmax first-occurrence semantics)
        float bv0 = -3.4e38f, bv1 = -3.4e38f, bv2 = -3.4e38f, bv3 = -3.4e38f;
        int bi0 = 0, bi1 = 1, bi2 = 2, bi3 = 3;
#pragma unroll
        for (int k = 0; k < 16; ++k) {
            float4 dd = dv[k];
            float v0 = dd.x + lA[4 * k + 0];
            float v1 = dd.y + lA[4 * k + 1];
            float v2 = dd.z + lA[4 * k + 2];
            float v3 = dd.w + lA[4 * k + 3];
            if (v0 > bv0) { bv0 = v0; bi0 = 4 * k + 0; }
            if (v1 > bv1) { bv1 = v1; bi1 = 4 * k + 1; }
            if (v2 > bv2) { bv2 = v2; bi2 = 4 * k + 2; }
            if (v3 > bv3) { bv3 = v3; bi3 = 4 * k + 3; }
        }
        float best = bv0; int bidx = bi0;
        if (bv1 > best || (bv1 == best && bi1 < bidx)) { best = bv1; bidx = bi1; }
        if (bv2 > best || (bv2 == best && bi2 < bidx)) { best = bv2; bidx = bi2; }
        if (bv3 > best || (bv3 == best && bi3 < bidx)) { best = bv3; bidx = bi3; }

        psi[((size_t)t * B_SZ + b) * 64 + j] = (unsigned char)bidx;
    }
}

// ===== per-chunk backpointer composition: wave per (b, g) =====
extern "C" __global__ __launch_bounds__(256)
void hmm_compose(const unsigned char* __restrict__ psi,
                 unsigned char* __restrict__ mt)
{
    const int w = blockIdx.x * 4 + (threadIdx.x >> 6);   // 0 .. 4223
    const int j = threadIdx.x & 63;
    const int g = w % NCHUNK;
    const int b = w / NCHUNK;
    const int e = (g < NCHUNK - 1) ? g * 64 + 64 : (T_LEN - 1);
    int M = j;
    for (int t = e; t >= g * 64 + 1; --t)
        M = psi[((size_t)t * B_SZ + b) * 64 + M];
    mt[((size_t)g * B_SZ + b) * 64 + j] = (unsigned char)M;
}

// ===== boundary walk + parallel chunk fill: block per batch =====
extern "C" __global__ __launch_bounds__(64, 1)
void hmm_fill(const unsigned char* __restrict__ psi,
              const unsigned char* __restrict__ mt,
              const int* __restrict__ c_last,
              float* __restrict__ out)
{
    __shared__ int sb[NCHUNK];       // sb[g] = state at t = 64*g
    const int b = blockIdx.x;
    const int g = threadIdx.x;
    const int cl = c_last[b];
    if (g == 0) {
        int cur = cl;
        for (int q = NCHUNK - 1; q >= 0; --q) {
            cur = mt[((size_t)q * B_SZ + b) * 64 + cur];
            sb[q] = cur;
        }
    }
    cfence();   // single wave, in-order DS
    float* oc = out + B_SZ + (size_t)b * T_LEN;
    if (g == NCHUNK) {
        oc[T_LEN - 1] = (float)cl;
    } else if (g < NCHUNK) {
        const int e = (g < NCHUNK - 1) ? g * 64 + 64 : (T_LEN - 1);
        int s = (g < NCHUNK - 1) ? sb[g + 1] : cl;
        for (int t = e; t >= g * 64 + 1; --t) {
            s = psi[((size_t)t * B_SZ + b) * 64 + s];
            oc[t - 1] = (float)s;
        }
    }
}

extern "C" void kernel_launch(void* const* d_in, const int* in_sizes, int n_in,
                              void* d_out, int out_size, void* d_ws, size_t ws_size,
                              hipStream_t stream)
{
    const float* x      = (const float*)d_in[0];
    const float* means  = (const float*)d_in[1];
    const float* stds   = (const float*)d_in[2];
    const float* logA   = (const float*)d_in[3];
    const float* logpi  = (const float*)d_in[4];
    float* out = (float*)d_out;

    // workspace layout (round-5 proven to fit)
    char* base = (char*)d_ws;
    float*         dstore = (float*)base;                                  // 67,174,400
    unsigned char* psi    = (unsigned char*)(base + 67174400);             // 16,793,600
    unsigned char* mt     = (unsigned char*)(base + 83968000);             //    270,336
    int*           cl     = (int*)(base + 84238336);                       //        512
    float*         lAg    = (float*)(base + 84238848);                     //     16,384
    float*         lpig   = (float*)(base + 84255232);                     //        256

    hipLaunchKernelGGL(hmm_prep, dim3(1), dim3(64), 0, stream, logA, logpi, lAg, lpig);
    hipLaunchKernelGGL(hmm_main, dim3(2 * B_SZ), dim3(64), 0, stream,
                       x, means, stds, lAg, lpig, out, dstore, cl);
    hipLaunchKernelGGL(hmm_psi, dim3(512), dim3(256), 0, stream, dstore, lAg, psi);
    hipLaunchKernelGGL(hmm_compose, dim3((NCHUNK * B_SZ) / 4), dim3(256), 0, stream, psi, mt);
    hipLaunchKernelGGL(hmm_fill, dim3(B_SZ), dim3(64), 0, stream, psi, mt, cl, out);
}